// Round 3
// baseline (2579.890 us; speedup 1.0000x reference)
//
#include <hip/hip_runtime.h>
#include <hip/hip_bf16.h>

typedef unsigned short u16;
typedef __bf16 bf16x8 __attribute__((ext_vector_type(8)));
typedef float f32x4 __attribute__((ext_vector_type(4)));
typedef unsigned int u32x4 __attribute__((ext_vector_type(4)));

#define DEVI __device__ __forceinline__

typedef __attribute__((address_space(3))) void lds_void;
typedef __attribute__((address_space(1))) const void gbl_void;

// async global->LDS, 16B per lane (global_load_lds_dwordx4)
DEVI void gload16(const void* gp, void* lp) {
    __builtin_amdgcn_global_load_lds((gbl_void*)gp, (lds_void*)lp, 16, 0, 0);
}

// fp32 -> bf16 round-to-nearest-even
DEVI u16 f2b(float f) {
    unsigned int u = __builtin_bit_cast(unsigned int, f);
    unsigned int lsb = (u >> 16) & 1u;
    u += 0x7fffu + lsb;
    return (u16)(u >> 16);
}
DEVI float b2f(u16 b) {
    unsigned int u = ((unsigned int)b) << 16;
    return __builtin_bit_cast(float, u);
}

// native exp2 (v_exp_f32)
DEVI float fexp2(float x) {
#if __has_builtin(__builtin_amdgcn_exp2f)
    return __builtin_amdgcn_exp2f(x);
#else
    return __expf(x * 0.6931471805599453f);
#endif
}

// XCD-chunk swizzle (T1, m157/m204): hardware-consecutive blocks round-robin
// over 8 XCDs; remap so each XCD executes a CONTIGUOUS chunk of logical tile
// ids -> blocks sharing an A row-panel run on the same XCD and hit its L2.
// Bijective iff nwg%8==0 (all our GEMM grids are); else identity.
DEVI void swz_block(int& bx, int& by, int& bz) {
    const int gx = gridDim.x, gy = gridDim.y;
    const int nwg = gx * gy * (int)gridDim.z;
    int hw = blockIdx.x + gx * (blockIdx.y + gy * blockIdx.z);
    int id = (nwg & 7) ? hw : ((hw & 7) * (nwg >> 3) + (hw >> 3));
    bx = id % gx;
    int t = id / gx;
    by = t % gy;
    bz = t / gy;
}

DEVI float blockReduceSum(float v, float* red, int tid) {
    #pragma unroll
    for (int o = 32; o; o >>= 1) v += __shfl_xor(v, o);
    __syncthreads();
    if ((tid & 63) == 0) red[tid >> 6] = v;
    __syncthreads();
    return red[0] + red[1] + red[2] + red[3];
}

// ---------------------------------------------------------------------------
// Detect input dtype: flag=1 if float inputs are bf16, 0 if fp32.
// ---------------------------------------------------------------------------
__global__ void detect_kernel(const void* tok, int* flag) {
    __shared__ int bad;
    if (threadIdx.x == 0) bad = 0;
    __syncthreads();
    const u16* p = (const u16*)tok;
    int cnt = 0;
    for (int j = 0; j < 16; ++j) {
        float v = b2f(p[2 * (threadIdx.x * 16 + j)]);
        if (!(fabsf(v) < 1.0f)) cnt++;
    }
    if (cnt) atomicAdd(&bad, 1);
    __syncthreads();
    if (threadIdx.x == 0) flag[0] = (bad == 0) ? 1 : 0;
}

__global__ void to_f32_kernel(const void* src, float* dst, int n, const int* flag) {
    int i = blockIdx.x * 256 + threadIdx.x;
    if (i >= n) return;
    if (flag[0]) dst[i] = b2f(((const u16*)src)[i]);
    else         dst[i] = ((const float*)src)[i];
}

// ---------------------------------------------------------------------------
// Core bf16 GEMM, async staging (m97 pattern): C(128,128) += A @ Bt^T.
// BK=32; 256 threads; per K-iter each wave issues 2 A- and 2 B-
// global_load_lds_dwordx4 (wave-uniform LDS base + lane*16B, packed rows of
// 32 u16). K % 32 == 0; rows 16B-aligned.
// ---------------------------------------------------------------------------
DEVI void gemm_core_async(const u16* __restrict__ A, int lda,
                          const u16* __restrict__ Bt, int ldb,
                          int K, f32x4 (&acc)[4][4],
                          u16* As, u16* Bs)
{
    const int tid  = threadIdx.x;
    const int lane = tid & 63;
    const int wave = tid >> 6;
    const int quad = lane >> 4;
    const int l16  = lane & 15;
    const int wm   = wave >> 1;
    const int wn   = wave & 1;

    // chunk indices this wave stages: instr i covers chunks (wave*2+i)*64+lane
    const int c0 = (wave * 2 + 0) * 64 + lane;
    const int c1 = (wave * 2 + 1) * 64 + lane;
    const int r0 = c0 >> 2, h0 = (c0 & 3) * 8;
    const int r1 = c1 >> 2, h1 = (c1 & 3) * 8;

    for (int k0 = 0; k0 < K; k0 += 32) {
        __syncthreads();   // prior iter's LDS reads drained before overwrite
        gload16(A  + (size_t)r0 * lda + k0 + h0, As + c0 * 8);
        gload16(Bt + (size_t)r0 * ldb + k0 + h0, Bs + c0 * 8);
        gload16(A  + (size_t)r1 * lda + k0 + h1, As + c1 * 8);
        gload16(Bt + (size_t)r1 * ldb + k0 + h1, Bs + c1 * 8);
        __syncthreads();   // compiler inserts vmcnt(0) drain before barrier

        bf16x8 af[4], bfv[4];
        #pragma unroll
        for (int mt = 0; mt < 4; ++mt)
            af[mt] = *(const bf16x8*)(As + (wm * 64 + mt * 16 + l16) * 32 + quad * 8);
        #pragma unroll
        for (int nt = 0; nt < 4; ++nt)
            bfv[nt] = *(const bf16x8*)(Bs + (wn * 64 + nt * 16 + l16) * 32 + quad * 8);
        #pragma unroll
        for (int mt = 0; mt < 4; ++mt)
            #pragma unroll
            for (int nt = 0; nt < 4; ++nt)
                acc[mt][nt] = __builtin_amdgcn_mfma_f32_16x16x32_bf16(af[mt], bfv[nt], acc[mt][nt], 0, 0, 0);
    }
}

// EPI: 0 = bf16 out (+bias), 1 = bf16 relu (+bias)
template<int EPI>
__global__ __launch_bounds__(256) void gemm_std(
    const u16* __restrict__ A, int lda,
    const u16* __restrict__ Bt, int ldb,
    const float* __restrict__ bias,
    u16* __restrict__ outB, int ldc, int K)
{
    __shared__ u16 As[128 * 32];
    __shared__ u16 Bs[128 * 32];
    int bx, by, bz;
    swz_block(bx, by, bz);
    const size_t bM = (size_t)by * 128;
    const size_t bN = (size_t)bx * 128;
    f32x4 acc[4][4] = {};
    gemm_core_async(A + bM * lda, lda, Bt + bN * ldb, ldb, K, acc, As, Bs);

    const int tid = threadIdx.x, lane = tid & 63, wave = tid >> 6;
    const int wm = wave >> 1, wn = wave & 1, quad = lane >> 4, l16 = lane & 15;
    #pragma unroll
    for (int mt = 0; mt < 4; ++mt)
        #pragma unroll
        for (int nt = 0; nt < 4; ++nt) {
            size_t col = bN + wn * 64 + nt * 16 + l16;
            float bcol = bias[col];
            #pragma unroll
            for (int r = 0; r < 4; ++r) {
                size_t row = bM + wm * 64 + mt * 16 + quad * 4 + r;
                float v = acc[mt][nt][r] + bcol;
                if constexpr (EPI == 1) v = fmaxf(v, 0.f);
                outB[row * ldc + col] = f2b(v);
            }
        }
}

// Split-K GEMM accumulating into fp32 residual via atomicAdd.
// logical z = split index; bias applied by split 0 only.
__global__ __launch_bounds__(256) void gemm_splitk(
    const u16* __restrict__ A, int lda,
    const u16* __restrict__ Bt, int ldb,
    const float* __restrict__ bias,
    float* __restrict__ resid, int ldc, int Ksub)
{
    __shared__ u16 As[128 * 32];
    __shared__ u16 Bs[128 * 32];
    int bx, by, bz;
    swz_block(bx, by, bz);
    const size_t bM = (size_t)by * 128;
    const size_t bN = (size_t)bx * 128;
    const int Koff = bz * Ksub;
    f32x4 acc[4][4] = {};
    gemm_core_async(A + bM * lda + Koff, lda, Bt + bN * ldb + Koff, ldb, Ksub, acc, As, Bs);

    const int tid = threadIdx.x, lane = tid & 63, wave = tid >> 6;
    const int wm = wave >> 1, wn = wave & 1, quad = lane >> 4, l16 = lane & 15;
    const bool addb = (bz == 0);
    #pragma unroll
    for (int mt = 0; mt < 4; ++mt)
        #pragma unroll
        for (int nt = 0; nt < 4; ++nt) {
            size_t col = bN + wn * 64 + nt * 16 + l16;
            float bcol = addb ? bias[col] : 0.f;
            #pragma unroll
            for (int r = 0; r < 4; ++r) {
                size_t row = bM + wm * 64 + mt * 16 + quad * 4 + r;
                atomicAdd(&resid[row * ldc + col], acc[mt][nt][r] + bcol);
            }
        }
}

// ---------------------------------------------------------------------------
// Flash attention: one block = one (b,h) x 128 q-rows. 256 thr (4 waves).
// LDS = 51200B -> 3 blocks/CU by LDS (grid is exactly 3 blocks/CU, one
// balanced residency round). Launch bounds (256,2): (256,3) forced the
// allocator below the live set -> 84 VGPR + scratch spill, 2x slower.
// All tiles XOR-swizzled at 16B-slot granularity (slot ^= row&7).
// P round-trips LDS in two 64-key halves (wave-private rows, no barrier).
// Softmax in exp2 domain with additive bf16 mask bias folded via fma.
// ---------------------------------------------------------------------------
__global__ __launch_bounds__(256, 2) void flash_attn(
    const u16* __restrict__ qkv, const u16* __restrict__ vt,
    const int* __restrict__ mask, u16* __restrict__ attout)
{
    __shared__ u16 Ks[128 * 64];    // [key][d]   128B rows, swizzled   16KB
    __shared__ u16 Vs[64 * 128];    // [d][key]   256B rows, swizzled   16KB
    __shared__ u16 Ps[128 * 64];    // [q][key-half] 128B rows, swizzled 16KB
    __shared__ u16 Msb[1024];       // additive bias bf16: masked -> -1e9, else 0

    const int bh = blockIdx.y;
    const int b = bh / 12, h = bh % 12;
    const int q0 = blockIdx.x * 128;
    const int tid = threadIdx.x, lane = tid & 63, wave = tid >> 6;
    const int quad = lane >> 4, l16 = lane & 15;
    const int sw = l16 & 7;         // read-side swizzle key (row&7 == l16&7)

    for (int i = tid; i < 1024; i += 256)
        Msb[i] = (mask[b * 1024 + i] != 0) ? f2b(-1e9f) : (u16)0;

    bf16x8 aq[2][2];
    #pragma unroll
    for (int mt = 0; mt < 2; ++mt)
        #pragma unroll
        for (int s = 0; s < 2; ++s)
            aq[mt][s] = *(const bf16x8*)(qkv + (size_t)(b * 1024 + q0 + wave * 32 + mt * 16 + l16) * 2304
                                          + h * 192 + s * 32 + quad * 8);

    const float SC2 = 0.18033688011112042f;   // 0.125 * log2(e): softmax in exp2 domain

    float mi[2][4], li[2][4];
    f32x4 Oacc[2][4] = {};
    #pragma unroll
    for (int mt = 0; mt < 2; ++mt)
        #pragma unroll
        for (int r = 0; r < 4; ++r) { mi[mt][r] = -3e38f; li[mt][r] = 0.f; }

    for (int kt = 0; kt < 8; ++kt) {
        u32x4 kreg[4], vreg[4];
        #pragma unroll
        for (int i = 0; i < 4; ++i) {
            int id = i * 256 + tid, row = id >> 3, ch = id & 7;
            kreg[i] = *(const u32x4*)(qkv + (size_t)(b * 1024 + kt * 128 + row) * 2304 + h * 192 + 64 + ch * 8);
        }
        #pragma unroll
        for (int i = 0; i < 4; ++i) {
            int id = i * 256 + tid, row = id >> 4, ch = id & 15;
            vreg[i] = *(const u32x4*)(vt + (size_t)bh * 65536 + (size_t)row * 1024 + kt * 128 + ch * 8);
        }
        __syncthreads();
        #pragma unroll
        for (int i = 0; i < 4; ++i) {
            int id = i * 256 + tid, row = id >> 3, ch = id & 7;
            *(u32x4*)(Ks + row * 64 + ((ch ^ (row & 7)) * 8)) = kreg[i];
        }
        #pragma unroll
        for (int i = 0; i < 4; ++i) {
            int id = i * 256 + tid, row = id >> 4, ch = id & 15;
            *(u32x4*)(Vs + row * 128 + ((ch ^ (row & 7)) * 8)) = vreg[i];
        }
        __syncthreads();

        f32x4 Sacc[2][8] = {};
        #pragma unroll
        for (int s = 0; s < 2; ++s) {
            bf16x8 kf[8];
            #pragma unroll
            for (int nt = 0; nt < 8; ++nt)
                kf[nt] = *(const bf16x8*)(Ks + (nt * 16 + l16) * 64 + (((s * 4 + quad) ^ sw) * 8));
            #pragma unroll
            for (int mt = 0; mt < 2; ++mt)
                #pragma unroll
                for (int nt = 0; nt < 8; ++nt)
                    Sacc[mt][nt] = __builtin_amdgcn_mfma_f32_16x16x32_bf16(aq[mt][s], kf[nt], Sacc[mt][nt], 0, 0, 0);
        }

        // scale (exp2 domain) + additive mask bias in one fma per element
        float bias[8];
        #pragma unroll
        for (int nt = 0; nt < 8; ++nt) bias[nt] = b2f(Msb[kt * 128 + nt * 16 + l16]);
        #pragma unroll
        for (int mt = 0; mt < 2; ++mt)
            #pragma unroll
            for (int nt = 0; nt < 8; ++nt)
                #pragma unroll
                for (int r = 0; r < 4; ++r)
                    Sacc[mt][nt][r] = fmaf(Sacc[mt][nt][r], SC2, bias[nt]);

        #pragma unroll
        for (int mt = 0; mt < 2; ++mt) {
            float al[4];
            #pragma unroll
            for (int r = 0; r < 4; ++r) {
                float rm = fmaxf(
                    fmaxf(fmaxf(Sacc[mt][0][r], Sacc[mt][1][r]), fmaxf(Sacc[mt][2][r], Sacc[mt][3][r])),
                    fmaxf(fmaxf(Sacc[mt][4][r], Sacc[mt][5][r]), fmaxf(Sacc[mt][6][r], Sacc[mt][7][r])));
                #pragma unroll
                for (int o = 8; o; o >>= 1) rm = fmaxf(rm, __shfl_xor(rm, o));
                float mn = fmaxf(mi[mt][r], rm);
                al[r] = fexp2(mi[mt][r] - mn);
                mi[mt][r] = mn;
                float rs = 0.f;
                #pragma unroll
                for (int nt = 0; nt < 8; ++nt) {
                    float pv = fexp2(Sacc[mt][nt][r] - mn);
                    rs += pv;
                    Sacc[mt][nt][r] = pv;
                }
                #pragma unroll
                for (int o = 8; o; o >>= 1) rs += __shfl_xor(rs, o);
                li[mt][r] = li[mt][r] * al[r] + rs;
            }
            #pragma unroll
            for (int ntv = 0; ntv < 4; ++ntv)
                #pragma unroll
                for (int r = 0; r < 4; ++r) Oacc[mt][ntv][r] *= al[r];
        }

        // P -> LDS -> PV in two 64-key halves (wave-private rows; DS in-order
        // per wave + compiler aliasing keeps write-after-read correct)
        #pragma unroll
        for (int hf = 0; hf < 2; ++hf) {
            #pragma unroll
            for (int mt = 0; mt < 2; ++mt) {
                const int rowb = wave * 32 + mt * 16 + quad * 4;
                #pragma unroll
                for (int n4 = 0; n4 < 4; ++n4) {
                    const int slot = n4 * 2 + (l16 >> 3);
                    #pragma unroll
                    for (int r = 0; r < 4; ++r) {
                        const int row = rowb + r;
                        Ps[row * 64 + ((slot ^ (row & 7)) * 8) + sw] = f2b(Sacc[mt][hf * 4 + n4][r]);
                    }
                }
            }
            #pragma unroll
            for (int s2h = 0; s2h < 2; ++s2h) {
                const int s2 = hf * 2 + s2h;
                bf16x8 vf[4];
                #pragma unroll
                for (int ntv = 0; ntv < 4; ++ntv)
                    vf[ntv] = *(const bf16x8*)(Vs + (ntv * 16 + l16) * 128 + (((s2 * 4 + quad) ^ sw) * 8));
                #pragma unroll
                for (int mt2 = 0; mt2 < 2; ++mt2) {
                    bf16x8 pf = *(const bf16x8*)(Ps + (wave * 32 + mt2 * 16 + l16) * 64 + (((s2h * 4 + quad) ^ sw) * 8));
                    #pragma unroll
                    for (int ntv = 0; ntv < 4; ++ntv)
                        Oacc[mt2][ntv] = __builtin_amdgcn_mfma_f32_16x16x32_bf16(pf, vf[ntv], Oacc[mt2][ntv], 0, 0, 0);
                }
            }
        }
    }

    #pragma unroll
    for (int mt = 0; mt < 2; ++mt)
        #pragma unroll
        for (int r = 0; r < 4; ++r) {
            float inv = 1.0f / li[mt][r];
            int s = q0 + wave * 32 + mt * 16 + quad * 4 + r;
            #pragma unroll
            for (int ntv = 0; ntv < 4; ++ntv)
                attout[((size_t)(b * 1024 + s)) * 768 + h * 64 + ntv * 16 + l16] = f2b(Oacc[mt][ntv][r] * inv);
        }
}

// x[b,s,:] = (token_emb[id] + pos_emb[s]) * sqrt(768)  (dual dtype)
__global__ __launch_bounds__(256) void embed_kernel(
    const int* __restrict__ ids, const void* __restrict__ tok,
    const void* __restrict__ pos, float* __restrict__ x, const int* __restrict__ flag)
{
    const int e  = blockIdx.x * 256 + threadIdx.x;
    const int bs = e / 192;
    const int d  = (e - bs * 192) * 4;
    const int s  = bs & 1023;
    const int id = ids[bs];
    float t[4], p4[4];
    if (flag[0]) {
        const u16* tb = (const u16*)tok + (size_t)id * 768 + d;
        const u16* pb = (const u16*)pos + (size_t)s  * 768 + d;
        #pragma unroll
        for (int j = 0; j < 4; ++j) { t[j] = b2f(tb[j]); p4[j] = b2f(pb[j]); }
    } else {
        const float* tb = (const float*)tok + (size_t)id * 768 + d;
        const float* pb = (const float*)pos + (size_t)s  * 768 + d;
        #pragma unroll
        for (int j = 0; j < 4; ++j) { t[j] = tb[j]; p4[j] = pb[j]; }
    }
    float* xo = x + (size_t)bs * 768 + d;
    #pragma unroll
    for (int j = 0; j < 4; ++j) xo[j] = (t[j] + p4[j]) * 27.7128129211020f;
}

__global__ __launch_bounds__(256) void layernorm_kernel(
    const float* __restrict__ x, const float* __restrict__ sc,
    const float* __restrict__ bi, u16* __restrict__ out)
{
    __shared__ float red[4];
    const size_t row = blockIdx.x;
    const float* xr = x + row * 768;
    const int tid = threadIdx.x;
    float v0 = xr[tid], v1 = xr[tid + 256], v2 = xr[tid + 512];
    float s = blockReduceSum(v0 + v1 + v2, red, tid);
    float mean = s * (1.0f / 768.0f);
    float d0 = v0 - mean, d1 = v1 - mean, d2 = v2 - mean;
    float q = blockReduceSum(d0 * d0 + d1 * d1 + d2 * d2, red, tid);
    float rstd = rsqrtf(q * (1.0f / 768.0f) + 1e-5f);
    u16* orow = out + row * 768;
    orow[tid]       = f2b(d0 * rstd * sc[tid]       + bi[tid]);
    orow[tid + 256] = f2b(d1 * rstd * sc[tid + 256] + bi[tid + 256]);
    orow[tid + 512] = f2b(d2 * rstd * sc[tid + 512] + bi[tid + 512]);
}

// W (Kd,Nd) [fp32 or bf16 per flag] -> Wt (Nd,Kd) bf16; one layer per launch
__global__ __launch_bounds__(256) void transpose_w_kernel(
    const void* __restrict__ W, size_t off, u16* __restrict__ Wt,
    int Kd, int Nd, const int* __restrict__ flag)
{
    __shared__ u16 tile[32][34];
    const int n0 = blockIdx.x * 32, k0 = blockIdx.y * 32;
    const int tx = threadIdx.x & 31, ty = threadIdx.x >> 5;
    const int fl = flag[0];
    #pragma unroll
    for (int i = 0; i < 4; ++i) {
        size_t idx = off + (size_t)(k0 + ty + i * 8) * Nd + n0 + tx;
        u16 val = fl ? ((const u16*)W)[idx] : f2b(((const float*)W)[idx]);
        tile[ty + i * 8][tx] = val;
    }
    __syncthreads();
    #pragma unroll
    for (int i = 0; i < 4; ++i)
        Wt[(size_t)(n0 + ty + i * 8) * Kd + k0 + tx] = tile[tx][ty + i * 8];
}

// vt[bh, d, t] = qkv[b, t, h*192+128+d]
__global__ __launch_bounds__(256) void build_vt_kernel(
    const u16* __restrict__ qkv, u16* __restrict__ vt)
{
    __shared__ u16 tile[64][72];
    const int bh = blockIdx.y;
    const int b = bh / 12, h = bh % 12;
    const int t0 = blockIdx.x * 64;
    const int tid = threadIdx.x;
    const int tl = tid >> 2;
    const int d4 = (tid & 3) * 16;
    const u16* src = qkv + (size_t)(b * 1024 + t0 + tl) * 2304 + h * 192 + 128 + d4;
    *(u32x4*)(&tile[tl][d4])     = *(const u32x4*)(src);
    *(u32x4*)(&tile[tl][d4 + 8]) = *(const u32x4*)(src + 8);
    __syncthreads();
    const int dd = tid >> 2;
    const int tstart = (tid & 3) * 16;
    union { u16 us[16]; u32x4 v[2]; } pk;
    #pragma unroll
    for (int j = 0; j < 16; ++j) pk.us[j] = tile[tstart + j][dd];
    u16* dst = vt + ((size_t)bh * 64 + dd) * 1024 + t0 + tstart;
    *(u32x4*)(dst)     = pk.v[0];
    *(u32x4*)(dst + 8) = pk.v[1];
}

// pooled = LN(x[:,0,:]); out = pooled @ cls_w + cls_b ; output dtype per flag
__global__ __launch_bounds__(256) void pooled_cls_kernel(
    const float* __restrict__ x, const float* __restrict__ hs, const float* __restrict__ hb,
    const float* __restrict__ cw, const float* __restrict__ cb, void* __restrict__ dout,
    const int* __restrict__ flag)
{
    __shared__ float red[4];
    __shared__ float pooled[768];
    const int b = blockIdx.x;
    const float* xr = x + (size_t)b * 1024 * 768;
    const int tid = threadIdx.x;
    float v0 = xr[tid], v1 = xr[tid + 256], v2 = xr[tid + 512];
    float s = blockReduceSum(v0 + v1 + v2, red, tid);
    float mean = s * (1.0f / 768.0f);
    float d0 = v0 - mean, d1 = v1 - mean, d2 = v2 - mean;
    float q = blockReduceSum(d0 * d0 + d1 * d1 + d2 * d2, red, tid);
    float rstd = rsqrtf(q * (1.0f / 768.0f) + 1e-5f);
    pooled[tid]       = d0 * rstd * hs[tid]       + hb[tid];
    pooled[tid + 256] = d1 * rstd * hs[tid + 256] + hb[tid + 256];
    pooled[tid + 512] = d2 * rstd * hs[tid + 512] + hb[tid + 512];
    __syncthreads();
    float p0 = 0.f, p1 = 0.f;
    for (int c = tid; c < 768; c += 256) {
        float pv = pooled[c];
        p0 += pv * cw[2 * c];
        p1 += pv * cw[2 * c + 1];
    }
    p0 = blockReduceSum(p0, red, tid);
    p1 = blockReduceSum(p1, red, tid);
    if (tid == 0) {
        float o0 = p0 + cb[0], o1 = p1 + cb[1];
        if (flag[0]) {
            ((u16*)dout)[b * 2 + 0] = f2b(o0);
            ((u16*)dout)[b * 2 + 1] = f2b(o1);
        } else {
            ((float*)dout)[b * 2 + 0] = o0;
            ((float*)dout)[b * 2 + 1] = o1;
        }
    }
}

extern "C" void kernel_launch(void* const* d_in, const int* in_sizes, int n_in,
                              void* d_out, int out_size, void* d_ws, size_t ws_size,
                              hipStream_t stream)
{
    const int* ids  = (const int*)d_in[0];
    const int* mask = (const int*)d_in[1];
    const void* tok   = d_in[2];
    const void* pos   = d_in[3];
    const void* qkv_w = d_in[4];
    const void* qkv_b = d_in[5];
    const void* out_w = d_in[6];
    const void* out_b = d_in[7];
    const void* n1_s  = d_in[8];
    const void* n1_b  = d_in[9];
    const void* ff1_w = d_in[10];
    const void* ff1_b = d_in[11];
    const void* ff2_w = d_in[12];
    const void* ff2_b = d_in[13];
    const void* n2_s  = d_in[14];
    const void* n2_b  = d_in[15];
    const void* hln_s = d_in[16];
    const void* hln_b = d_in[17];
    const void* cls_w = d_in[18];
    const void* cls_b = d_in[19];

    char* p = (char*)d_ws;
    auto alloc = [&](size_t bytes) -> char* {
        char* r = p; p += (bytes + 255) & ~(size_t)255; return r;
    };
    float* x      = (float*)alloc(6291456ull * 4);    // residual (B*S*D) fp32       25.2MB
    u16*   h      = (u16*)  alloc(6291456ull * 2);    // LN out / attout (shared)    12.6MB
    u16*   qkvB   = (u16*)  alloc(18874368ull * 2);   // qkv bf16 (B*S*2304)         37.7MB
    u16*   vt     = (u16*)  alloc(6291456ull * 2);    // V^T (96,64,1024)            12.6MB
    u16*   ffmid  = (u16*)  alloc(25165824ull * 2);   // (8192,3072) bf16            50.3MB
    u16*   wqkvT  = (u16*)  alloc(1769472ull * 2);    // (2304,768) one layer
    u16*   woutT  = (u16*)  alloc(589824ull * 2);     // (768,768)
    u16*   wff1T  = (u16*)  alloc(2359296ull * 2);    // (3072,768)
    u16*   wff2T  = (u16*)  alloc(2359296ull * 2);    // (768,3072)
    float* params = (float*)alloc(62978ull * 4);      // converted fp32 param vectors
    int*   flag   = (int*)  alloc(256);
    u16*   attout = h;                                 // aliases h (disjoint lifetime)

    float* P_qkv_b = params + 0;
    float* P_out_b = params + 13824;
    float* P_n1_s  = params + 18432;
    float* P_n1_b  = params + 23040;
    float* P_ff1_b = params + 27648;
    float* P_ff2_b = params + 46080;
    float* P_n2_s  = params + 50688;
    float* P_n2_b  = params + 55296;
    float* P_hln_s = params + 59904;
    float* P_hln_b = params + 60672;
    float* P_cls_w = params + 61440;
    float* P_cls_b = params + 62976;

    detect_kernel<<<1, 256, 0, stream>>>(tok, flag);

    auto cvt = [&](const void* src, float* dst, int n) {
        to_f32_kernel<<<(n + 255) / 256, 256, 0, stream>>>(src, dst, n, flag);
    };
    cvt(qkv_b, P_qkv_b, 13824);  cvt(out_b, P_out_b, 4608);
    cvt(n1_s,  P_n1_s,  4608);   cvt(n1_b,  P_n1_b,  4608);
    cvt(ff1_b, P_ff1_b, 18432);  cvt(ff2_b, P_ff2_b, 4608);
    cvt(n2_s,  P_n2_s,  4608);   cvt(n2_b,  P_n2_b,  4608);
    cvt(hln_s, P_hln_s, 768);    cvt(hln_b, P_hln_b, 768);
    cvt(cls_w, P_cls_w, 1536);   cvt(cls_b, P_cls_b, 2);

    embed_kernel<<<6144, 256, 0, stream>>>(ids, tok, pos, x, flag);

    for (int l = 0; l < 6; ++l) {
        transpose_w_kernel<<<dim3(72, 24), 256, 0, stream>>>(qkv_w, (size_t)l * 1769472, wqkvT, 768, 2304, flag);
        transpose_w_kernel<<<dim3(24, 24), 256, 0, stream>>>(out_w, (size_t)l * 589824,  woutT, 768, 768,  flag);
        transpose_w_kernel<<<dim3(96, 24), 256, 0, stream>>>(ff1_w, (size_t)l * 2359296, wff1T, 768, 3072, flag);
        transpose_w_kernel<<<dim3(24, 96), 256, 0, stream>>>(ff2_w, (size_t)l * 2359296, wff2T, 3072, 768, flag);

        layernorm_kernel<<<8192, 256, 0, stream>>>(x, P_n1_s + l * 768, P_n1_b + l * 768, h);
        gemm_std<0><<<dim3(18, 64), 256, 0, stream>>>(h, 768, wqkvT, 768,
                                                      P_qkv_b + l * 2304, qkvB, 2304, 768);
        build_vt_kernel<<<dim3(16, 96), 256, 0, stream>>>(qkvB, vt);
        flash_attn<<<dim3(8, 96), 256, 0, stream>>>(qkvB, vt, mask, attout);
        gemm_splitk<<<dim3(6, 64, 2), 256, 0, stream>>>(attout, 768, woutT, 768,
                                                        P_out_b + l * 768, x, 768, 384);
        layernorm_kernel<<<8192, 256, 0, stream>>>(x, P_n2_s + l * 768, P_n2_b + l * 768, h);
        gemm_std<1><<<dim3(24, 64), 256, 0, stream>>>(h, 768, wff1T, 768,
                                                      P_ff1_b + l * 3072, ffmid, 3072, 768);
        // ff2: split-K 4 (Ksub=768) -> 1536 blocks = 6/CU for latency overlap
        gemm_splitk<<<dim3(6, 64, 4), 256, 0, stream>>>(ffmid, 3072, wff2T, 3072,
                                                        P_ff2_b + l * 768, x, 768, 768);
    }
    pooled_cls_kernel<<<8, 256, 0, stream>>>(x, P_hln_s, P_hln_b, P_cls_w, P_cls_b, d_out, flag);
}

// Round 4
// 2382.506 us; speedup vs baseline: 1.0828x; 1.0828x over previous
//
#include <hip/hip_runtime.h>
#include <hip/hip_bf16.h>

typedef unsigned short u16;
typedef __bf16 bf16x8 __attribute__((ext_vector_type(8)));
typedef float f32x4 __attribute__((ext_vector_type(4)));
typedef unsigned int u32x4 __attribute__((ext_vector_type(4)));

#define DEVI __device__ __forceinline__

typedef __attribute__((address_space(3))) void lds_void;
typedef __attribute__((address_space(1))) const void gbl_void;

// async global->LDS, 16B per lane (global_load_lds_dwordx4)
DEVI void gload16(const void* gp, void* lp) {
    __builtin_amdgcn_global_load_lds((gbl_void*)gp, (lds_void*)lp, 16, 0, 0);
}

// fp32 -> bf16 round-to-nearest-even
DEVI u16 f2b(float f) {
    unsigned int u = __builtin_bit_cast(unsigned int, f);
    unsigned int lsb = (u >> 16) & 1u;
    u += 0x7fffu + lsb;
    return (u16)(u >> 16);
}
DEVI float b2f(u16 b) {
    unsigned int u = ((unsigned int)b) << 16;
    return __builtin_bit_cast(float, u);
}

// native exp2 (v_exp_f32)
DEVI float fexp2(float x) {
#if __has_builtin(__builtin_amdgcn_exp2f)
    return __builtin_amdgcn_exp2f(x);
#else
    return __expf(x * 0.6931471805599453f);
#endif
}

// XCD-chunk swizzle (T1), 2D-only + z-passthrough. Hardware round-robins
// consecutive blocks over 8 XCDs; remap (bx,by) so each XCD gets a
// CONTIGUOUS chunk of 2D tile ids -> blocks sharing an A row-panel hit the
// same XCD L2. z (split-K index) is passed through RAW: since gx*gy % 8 == 0,
// all z-splits of a tile map to the SAME XCD, ~chunk-stride apart in time ->
// same-address atomics are same-XCD (L2-local RMW) and time-separated.
// (Round-3 lesson: folding z into the chunk id put z-splits of one tile on
// DIFFERENT XCDs running CONCURRENTLY -> cross-XCD atomic ping-pong, +29%.)
// Bijective iff (gx*gy)%8==0 (all our GEMM grids); else identity.
DEVI void swz_block(int& bx, int& by, int& bz) {
    const int gx = gridDim.x, gy = gridDim.y;
    const int nwg2 = gx * gy;
    int hw = blockIdx.x + gx * blockIdx.y;
    int id = (nwg2 & 7) ? hw : ((hw & 7) * (nwg2 >> 3) + (hw >> 3));
    bx = id % gx;
    by = id / gx;
    bz = blockIdx.z;
}

DEVI float blockReduceSum(float v, float* red, int tid) {
    #pragma unroll
    for (int o = 32; o; o >>= 1) v += __shfl_xor(v, o);
    __syncthreads();
    if ((tid & 63) == 0) red[tid >> 6] = v;
    __syncthreads();
    return red[0] + red[1] + red[2] + red[3];
}

// ---------------------------------------------------------------------------
// Detect input dtype: flag=1 if float inputs are bf16, 0 if fp32.
// ---------------------------------------------------------------------------
__global__ void detect_kernel(const void* tok, int* flag) {
    __shared__ int bad;
    if (threadIdx.x == 0) bad = 0;
    __syncthreads();
    const u16* p = (const u16*)tok;
    int cnt = 0;
    for (int j = 0; j < 16; ++j) {
        float v = b2f(p[2 * (threadIdx.x * 16 + j)]);
        if (!(fabsf(v) < 1.0f)) cnt++;
    }
    if (cnt) atomicAdd(&bad, 1);
    __syncthreads();
    if (threadIdx.x == 0) flag[0] = (bad == 0) ? 1 : 0;
}

__global__ void to_f32_kernel(const void* src, float* dst, int n, const int* flag) {
    int i = blockIdx.x * 256 + threadIdx.x;
    if (i >= n) return;
    if (flag[0]) dst[i] = b2f(((const u16*)src)[i]);
    else         dst[i] = ((const float*)src)[i];
}

// ---------------------------------------------------------------------------
// Core bf16 GEMM, async staging (m97 pattern): C(128,128) += A @ Bt^T.
// BK=32; 256 threads; per K-iter each wave issues 2 A- and 2 B-
// global_load_lds_dwordx4 (wave-uniform LDS base + lane*16B, packed rows of
// 32 u16). K % 32 == 0; rows 16B-aligned.
// ---------------------------------------------------------------------------
DEVI void gemm_core_async(const u16* __restrict__ A, int lda,
                          const u16* __restrict__ Bt, int ldb,
                          int K, f32x4 (&acc)[4][4],
                          u16* As, u16* Bs)
{
    const int tid  = threadIdx.x;
    const int lane = tid & 63;
    const int wave = tid >> 6;
    const int quad = lane >> 4;
    const int l16  = lane & 15;
    const int wm   = wave >> 1;
    const int wn   = wave & 1;

    // chunk indices this wave stages: instr i covers chunks (wave*2+i)*64+lane
    const int c0 = (wave * 2 + 0) * 64 + lane;
    const int c1 = (wave * 2 + 1) * 64 + lane;
    const int r0 = c0 >> 2, h0 = (c0 & 3) * 8;
    const int r1 = c1 >> 2, h1 = (c1 & 3) * 8;

    for (int k0 = 0; k0 < K; k0 += 32) {
        __syncthreads();   // prior iter's LDS reads drained before overwrite
        gload16(A  + (size_t)r0 * lda + k0 + h0, As + c0 * 8);
        gload16(Bt + (size_t)r0 * ldb + k0 + h0, Bs + c0 * 8);
        gload16(A  + (size_t)r1 * lda + k0 + h1, As + c1 * 8);
        gload16(Bt + (size_t)r1 * ldb + k0 + h1, Bs + c1 * 8);
        __syncthreads();   // compiler inserts vmcnt(0) drain before barrier

        bf16x8 af[4], bfv[4];
        #pragma unroll
        for (int mt = 0; mt < 4; ++mt)
            af[mt] = *(const bf16x8*)(As + (wm * 64 + mt * 16 + l16) * 32 + quad * 8);
        #pragma unroll
        for (int nt = 0; nt < 4; ++nt)
            bfv[nt] = *(const bf16x8*)(Bs + (wn * 64 + nt * 16 + l16) * 32 + quad * 8);
        #pragma unroll
        for (int mt = 0; mt < 4; ++mt)
            #pragma unroll
            for (int nt = 0; nt < 4; ++nt)
                acc[mt][nt] = __builtin_amdgcn_mfma_f32_16x16x32_bf16(af[mt], bfv[nt], acc[mt][nt], 0, 0, 0);
    }
}

// EPI: 0 = bf16 out (+bias), 1 = bf16 relu (+bias)
template<int EPI>
__global__ __launch_bounds__(256) void gemm_std(
    const u16* __restrict__ A, int lda,
    const u16* __restrict__ Bt, int ldb,
    const float* __restrict__ bias,
    u16* __restrict__ outB, int ldc, int K)
{
    __shared__ u16 As[128 * 32];
    __shared__ u16 Bs[128 * 32];
    int bx, by, bz;
    swz_block(bx, by, bz);
    const size_t bM = (size_t)by * 128;
    const size_t bN = (size_t)bx * 128;
    f32x4 acc[4][4] = {};
    gemm_core_async(A + bM * lda, lda, Bt + bN * ldb, ldb, K, acc, As, Bs);

    const int tid = threadIdx.x, lane = tid & 63, wave = tid >> 6;
    const int wm = wave >> 1, wn = wave & 1, quad = lane >> 4, l16 = lane & 15;
    #pragma unroll
    for (int mt = 0; mt < 4; ++mt)
        #pragma unroll
        for (int nt = 0; nt < 4; ++nt) {
            size_t col = bN + wn * 64 + nt * 16 + l16;
            float bcol = bias[col];
            #pragma unroll
            for (int r = 0; r < 4; ++r) {
                size_t row = bM + wm * 64 + mt * 16 + quad * 4 + r;
                float v = acc[mt][nt][r] + bcol;
                if constexpr (EPI == 1) v = fmaxf(v, 0.f);
                outB[row * ldc + col] = f2b(v);
            }
        }
}

// Split-K GEMM accumulating into fp32 residual via atomicAdd.
// z = split index (passed through swz_block raw); bias applied by split 0.
__global__ __launch_bounds__(256) void gemm_splitk(
    const u16* __restrict__ A, int lda,
    const u16* __restrict__ Bt, int ldb,
    const float* __restrict__ bias,
    float* __restrict__ resid, int ldc, int Ksub)
{
    __shared__ u16 As[128 * 32];
    __shared__ u16 Bs[128 * 32];
    int bx, by, bz;
    swz_block(bx, by, bz);
    const size_t bM = (size_t)by * 128;
    const size_t bN = (size_t)bx * 128;
    const int Koff = bz * Ksub;
    f32x4 acc[4][4] = {};
    gemm_core_async(A + bM * lda + Koff, lda, Bt + bN * ldb + Koff, ldb, Ksub, acc, As, Bs);

    const int tid = threadIdx.x, lane = tid & 63, wave = tid >> 6;
    const int wm = wave >> 1, wn = wave & 1, quad = lane >> 4, l16 = lane & 15;
    const bool addb = (bz == 0);
    #pragma unroll
    for (int mt = 0; mt < 4; ++mt)
        #pragma unroll
        for (int nt = 0; nt < 4; ++nt) {
            size_t col = bN + wn * 64 + nt * 16 + l16;
            float bcol = addb ? bias[col] : 0.f;
            #pragma unroll
            for (int r = 0; r < 4; ++r) {
                size_t row = bM + wm * 64 + mt * 16 + quad * 4 + r;
                atomicAdd(&resid[row * ldc + col], acc[mt][nt][r] + bcol);
            }
        }
}

// ---------------------------------------------------------------------------
// Flash attention: one block = one (b,h) x 128 q-rows. 256 thr (4 waves).
// LDS = 51200B -> 3 blocks/CU by LDS (grid is exactly 3 blocks/CU, one
// balanced residency round). Launch bounds (256,2): (256,3) forced the
// allocator below the live set -> 84 VGPR + scratch spill, 2x slower.
// All tiles XOR-swizzled at 16B-slot granularity (slot ^= row&7).
// P round-trips LDS in two 64-key halves (wave-private rows, no barrier).
// Softmax in exp2 domain with additive bf16 mask bias folded via fma.
// ---------------------------------------------------------------------------
__global__ __launch_bounds__(256, 2) void flash_attn(
    const u16* __restrict__ qkv, const u16* __restrict__ vt,
    const int* __restrict__ mask, u16* __restrict__ attout)
{
    __shared__ u16 Ks[128 * 64];    // [key][d]   128B rows, swizzled   16KB
    __shared__ u16 Vs[64 * 128];    // [d][key]   256B rows, swizzled   16KB
    __shared__ u16 Ps[128 * 64];    // [q][key-half] 128B rows, swizzled 16KB
    __shared__ u16 Msb[1024];       // additive bias bf16: masked -> -1e9, else 0

    const int bh = blockIdx.y;
    const int b = bh / 12, h = bh % 12;
    const int q0 = blockIdx.x * 128;
    const int tid = threadIdx.x, lane = tid & 63, wave = tid >> 6;
    const int quad = lane >> 4, l16 = lane & 15;
    const int sw = l16 & 7;         // read-side swizzle key (row&7 == l16&7)

    for (int i = tid; i < 1024; i += 256)
        Msb[i] = (mask[b * 1024 + i] != 0) ? f2b(-1e9f) : (u16)0;

    bf16x8 aq[2][2];
    #pragma unroll
    for (int mt = 0; mt < 2; ++mt)
        #pragma unroll
        for (int s = 0; s < 2; ++s)
            aq[mt][s] = *(const bf16x8*)(qkv + (size_t)(b * 1024 + q0 + wave * 32 + mt * 16 + l16) * 2304
                                          + h * 192 + s * 32 + quad * 8);

    const float SC2 = 0.18033688011112042f;   // 0.125 * log2(e): softmax in exp2 domain

    float mi[2][4], li[2][4];
    f32x4 Oacc[2][4] = {};
    #pragma unroll
    for (int mt = 0; mt < 2; ++mt)
        #pragma unroll
        for (int r = 0; r < 4; ++r) { mi[mt][r] = -3e38f; li[mt][r] = 0.f; }

    for (int kt = 0; kt < 8; ++kt) {
        u32x4 kreg[4], vreg[4];
        #pragma unroll
        for (int i = 0; i < 4; ++i) {
            int id = i * 256 + tid, row = id >> 3, ch = id & 7;
            kreg[i] = *(const u32x4*)(qkv + (size_t)(b * 1024 + kt * 128 + row) * 2304 + h * 192 + 64 + ch * 8);
        }
        #pragma unroll
        for (int i = 0; i < 4; ++i) {
            int id = i * 256 + tid, row = id >> 4, ch = id & 15;
            vreg[i] = *(const u32x4*)(vt + (size_t)bh * 65536 + (size_t)row * 1024 + kt * 128 + ch * 8);
        }
        __syncthreads();
        #pragma unroll
        for (int i = 0; i < 4; ++i) {
            int id = i * 256 + tid, row = id >> 3, ch = id & 7;
            *(u32x4*)(Ks + row * 64 + ((ch ^ (row & 7)) * 8)) = kreg[i];
        }
        #pragma unroll
        for (int i = 0; i < 4; ++i) {
            int id = i * 256 + tid, row = id >> 4, ch = id & 15;
            *(u32x4*)(Vs + row * 128 + ((ch ^ (row & 7)) * 8)) = vreg[i];
        }
        __syncthreads();

        f32x4 Sacc[2][8] = {};
        #pragma unroll
        for (int s = 0; s < 2; ++s) {
            bf16x8 kf[8];
            #pragma unroll
            for (int nt = 0; nt < 8; ++nt)
                kf[nt] = *(const bf16x8*)(Ks + (nt * 16 + l16) * 64 + (((s * 4 + quad) ^ sw) * 8));
            #pragma unroll
            for (int mt = 0; mt < 2; ++mt)
                #pragma unroll
                for (int nt = 0; nt < 8; ++nt)
                    Sacc[mt][nt] = __builtin_amdgcn_mfma_f32_16x16x32_bf16(aq[mt][s], kf[nt], Sacc[mt][nt], 0, 0, 0);
        }

        // scale (exp2 domain) + additive mask bias in one fma per element
        float bias[8];
        #pragma unroll
        for (int nt = 0; nt < 8; ++nt) bias[nt] = b2f(Msb[kt * 128 + nt * 16 + l16]);
        #pragma unroll
        for (int mt = 0; mt < 2; ++mt)
            #pragma unroll
            for (int nt = 0; nt < 8; ++nt)
                #pragma unroll
                for (int r = 0; r < 4; ++r)
                    Sacc[mt][nt][r] = fmaf(Sacc[mt][nt][r], SC2, bias[nt]);

        #pragma unroll
        for (int mt = 0; mt < 2; ++mt) {
            float al[4];
            #pragma unroll
            for (int r = 0; r < 4; ++r) {
                float rm = fmaxf(
                    fmaxf(fmaxf(Sacc[mt][0][r], Sacc[mt][1][r]), fmaxf(Sacc[mt][2][r], Sacc[mt][3][r])),
                    fmaxf(fmaxf(Sacc[mt][4][r], Sacc[mt][5][r]), fmaxf(Sacc[mt][6][r], Sacc[mt][7][r])));
                #pragma unroll
                for (int o = 8; o; o >>= 1) rm = fmaxf(rm, __shfl_xor(rm, o));
                float mn = fmaxf(mi[mt][r], rm);
                al[r] = fexp2(mi[mt][r] - mn);
                mi[mt][r] = mn;
                float rs = 0.f;
                #pragma unroll
                for (int nt = 0; nt < 8; ++nt) {
                    float pv = fexp2(Sacc[mt][nt][r] - mn);
                    rs += pv;
                    Sacc[mt][nt][r] = pv;
                }
                #pragma unroll
                for (int o = 8; o; o >>= 1) rs += __shfl_xor(rs, o);
                li[mt][r] = li[mt][r] * al[r] + rs;
            }
            #pragma unroll
            for (int ntv = 0; ntv < 4; ++ntv)
                #pragma unroll
                for (int r = 0; r < 4; ++r) Oacc[mt][ntv][r] *= al[r];
        }

        // P -> LDS -> PV in two 64-key halves (wave-private rows; DS in-order
        // per wave + compiler aliasing keeps write-after-read correct)
        #pragma unroll
        for (int hf = 0; hf < 2; ++hf) {
            #pragma unroll
            for (int mt = 0; mt < 2; ++mt) {
                const int rowb = wave * 32 + mt * 16 + quad * 4;
                #pragma unroll
                for (int n4 = 0; n4 < 4; ++n4) {
                    const int slot = n4 * 2 + (l16 >> 3);
                    #pragma unroll
                    for (int r = 0; r < 4; ++r) {
                        const int row = rowb + r;
                        Ps[row * 64 + ((slot ^ (row & 7)) * 8) + sw] = f2b(Sacc[mt][hf * 4 + n4][r]);
                    }
                }
            }
            #pragma unroll
            for (int s2h = 0; s2h < 2; ++s2h) {
                const int s2 = hf * 2 + s2h;
                bf16x8 vf[4];
                #pragma unroll
                for (int ntv = 0; ntv < 4; ++ntv)
                    vf[ntv] = *(const bf16x8*)(Vs + (ntv * 16 + l16) * 128 + (((s2 * 4 + quad) ^ sw) * 8));
                #pragma unroll
                for (int mt2 = 0; mt2 < 2; ++mt2) {
                    bf16x8 pf = *(const bf16x8*)(Ps + (wave * 32 + mt2 * 16 + l16) * 64 + (((s2h * 4 + quad) ^ sw) * 8));
                    #pragma unroll
                    for (int ntv = 0; ntv < 4; ++ntv)
                        Oacc[mt2][ntv] = __builtin_amdgcn_mfma_f32_16x16x32_bf16(pf, vf[ntv], Oacc[mt2][ntv], 0, 0, 0);
                }
            }
        }
    }

    #pragma unroll
    for (int mt = 0; mt < 2; ++mt)
        #pragma unroll
        for (int r = 0; r < 4; ++r) {
            float inv = 1.0f / li[mt][r];
            int s = q0 + wave * 32 + mt * 16 + quad * 4 + r;
            #pragma unroll
            for (int ntv = 0; ntv < 4; ++ntv)
                attout[((size_t)(b * 1024 + s)) * 768 + h * 64 + ntv * 16 + l16] = f2b(Oacc[mt][ntv][r] * inv);
        }
}

// x[b,s,:] = (token_emb[id] + pos_emb[s]) * sqrt(768)  (dual dtype)
__global__ __launch_bounds__(256) void embed_kernel(
    const int* __restrict__ ids, const void* __restrict__ tok,
    const void* __restrict__ pos, float* __restrict__ x, const int* __restrict__ flag)
{
    const int e  = blockIdx.x * 256 + threadIdx.x;
    const int bs = e / 192;
    const int d  = (e - bs * 192) * 4;
    const int s  = bs & 1023;
    const int id = ids[bs];
    float t[4], p4[4];
    if (flag[0]) {
        const u16* tb = (const u16*)tok + (size_t)id * 768 + d;
        const u16* pb = (const u16*)pos + (size_t)s  * 768 + d;
        #pragma unroll
        for (int j = 0; j < 4; ++j) { t[j] = b2f(tb[j]); p4[j] = b2f(pb[j]); }
    } else {
        const float* tb = (const float*)tok + (size_t)id * 768 + d;
        const float* pb = (const float*)pos + (size_t)s  * 768 + d;
        #pragma unroll
        for (int j = 0; j < 4; ++j) { t[j] = tb[j]; p4[j] = pb[j]; }
    }
    float* xo = x + (size_t)bs * 768 + d;
    #pragma unroll
    for (int j = 0; j < 4; ++j) xo[j] = (t[j] + p4[j]) * 27.7128129211020f;
}

__global__ __launch_bounds__(256) void layernorm_kernel(
    const float* __restrict__ x, const float* __restrict__ sc,
    const float* __restrict__ bi, u16* __restrict__ out)
{
    __shared__ float red[4];
    const size_t row = blockIdx.x;
    const float* xr = x + row * 768;
    const int tid = threadIdx.x;
    float v0 = xr[tid], v1 = xr[tid + 256], v2 = xr[tid + 512];
    float s = blockReduceSum(v0 + v1 + v2, red, tid);
    float mean = s * (1.0f / 768.0f);
    float d0 = v0 - mean, d1 = v1 - mean, d2 = v2 - mean;
    float q = blockReduceSum(d0 * d0 + d1 * d1 + d2 * d2, red, tid);
    float rstd = rsqrtf(q * (1.0f / 768.0f) + 1e-5f);
    u16* orow = out + row * 768;
    orow[tid]       = f2b(d0 * rstd * sc[tid]       + bi[tid]);
    orow[tid + 256] = f2b(d1 * rstd * sc[tid + 256] + bi[tid + 256]);
    orow[tid + 512] = f2b(d2 * rstd * sc[tid + 512] + bi[tid + 512]);
}

// W (Kd,Nd) [fp32 or bf16 per flag] -> Wt (Nd,Kd) bf16; one layer per launch
__global__ __launch_bounds__(256) void transpose_w_kernel(
    const void* __restrict__ W, size_t off, u16* __restrict__ Wt,
    int Kd, int Nd, const int* __restrict__ flag)
{
    __shared__ u16 tile[32][34];
    const int n0 = blockIdx.x * 32, k0 = blockIdx.y * 32;
    const int tx = threadIdx.x & 31, ty = threadIdx.x >> 5;
    const int fl = flag[0];
    #pragma unroll
    for (int i = 0; i < 4; ++i) {
        size_t idx = off + (size_t)(k0 + ty + i * 8) * Nd + n0 + tx;
        u16 val = fl ? ((const u16*)W)[idx] : f2b(((const float*)W)[idx]);
        tile[ty + i * 8][tx] = val;
    }
    __syncthreads();
    #pragma unroll
    for (int i = 0; i < 4; ++i)
        Wt[(size_t)(n0 + ty + i * 8) * Kd + k0 + tx] = tile[tx][ty + i * 8];
}

// vt[bh, d, t] = qkv[b, t, h*192+128+d]
__global__ __launch_bounds__(256) void build_vt_kernel(
    const u16* __restrict__ qkv, u16* __restrict__ vt)
{
    __shared__ u16 tile[64][72];
    const int bh = blockIdx.y;
    const int b = bh / 12, h = bh % 12;
    const int t0 = blockIdx.x * 64;
    const int tid = threadIdx.x;
    const int tl = tid >> 2;
    const int d4 = (tid & 3) * 16;
    const u16* src = qkv + (size_t)(b * 1024 + t0 + tl) * 2304 + h * 192 + 128 + d4;
    *(u32x4*)(&tile[tl][d4])     = *(const u32x4*)(src);
    *(u32x4*)(&tile[tl][d4 + 8]) = *(const u32x4*)(src + 8);
    __syncthreads();
    const int dd = tid >> 2;
    const int tstart = (tid & 3) * 16;
    union { u16 us[16]; u32x4 v[2]; } pk;
    #pragma unroll
    for (int j = 0; j < 16; ++j) pk.us[j] = tile[tstart + j][dd];
    u16* dst = vt + ((size_t)bh * 64 + dd) * 1024 + t0 + tstart;
    *(u32x4*)(dst)     = pk.v[0];
    *(u32x4*)(dst + 8) = pk.v[1];
}

// pooled = LN(x[:,0,:]); out = pooled @ cls_w + cls_b ; output dtype per flag
__global__ __launch_bounds__(256) void pooled_cls_kernel(
    const float* __restrict__ x, const float* __restrict__ hs, const float* __restrict__ hb,
    const float* __restrict__ cw, const float* __restrict__ cb, void* __restrict__ dout,
    const int* __restrict__ flag)
{
    __shared__ float red[4];
    __shared__ float pooled[768];
    const int b = blockIdx.x;
    const float* xr = x + (size_t)b * 1024 * 768;
    const int tid = threadIdx.x;
    float v0 = xr[tid], v1 = xr[tid + 256], v2 = xr[tid + 512];
    float s = blockReduceSum(v0 + v1 + v2, red, tid);
    float mean = s * (1.0f / 768.0f);
    float d0 = v0 - mean, d1 = v1 - mean, d2 = v2 - mean;
    float q = blockReduceSum(d0 * d0 + d1 * d1 + d2 * d2, red, tid);
    float rstd = rsqrtf(q * (1.0f / 768.0f) + 1e-5f);
    pooled[tid]       = d0 * rstd * hs[tid]       + hb[tid];
    pooled[tid + 256] = d1 * rstd * hs[tid + 256] + hb[tid + 256];
    pooled[tid + 512] = d2 * rstd * hs[tid + 512] + hb[tid + 512];
    __syncthreads();
    float p0 = 0.f, p1 = 0.f;
    for (int c = tid; c < 768; c += 256) {
        float pv = pooled[c];
        p0 += pv * cw[2 * c];
        p1 += pv * cw[2 * c + 1];
    }
    p0 = blockReduceSum(p0, red, tid);
    p1 = blockReduceSum(p1, red, tid);
    if (tid == 0) {
        float o0 = p0 + cb[0], o1 = p1 + cb[1];
        if (flag[0]) {
            ((u16*)dout)[b * 2 + 0] = f2b(o0);
            ((u16*)dout)[b * 2 + 1] = f2b(o1);
        } else {
            ((float*)dout)[b * 2 + 0] = o0;
            ((float*)dout)[b * 2 + 1] = o1;
        }
    }
}

extern "C" void kernel_launch(void* const* d_in, const int* in_sizes, int n_in,
                              void* d_out, int out_size, void* d_ws, size_t ws_size,
                              hipStream_t stream)
{
    const int* ids  = (const int*)d_in[0];
    const int* mask = (const int*)d_in[1];
    const void* tok   = d_in[2];
    const void* pos   = d_in[3];
    const void* qkv_w = d_in[4];
    const void* qkv_b = d_in[5];
    const void* out_w = d_in[6];
    const void* out_b = d_in[7];
    const void* n1_s  = d_in[8];
    const void* n1_b  = d_in[9];
    const void* ff1_w = d_in[10];
    const void* ff1_b = d_in[11];
    const void* ff2_w = d_in[12];
    const void* ff2_b = d_in[13];
    const void* n2_s  = d_in[14];
    const void* n2_b  = d_in[15];
    const void* hln_s = d_in[16];
    const void* hln_b = d_in[17];
    const void* cls_w = d_in[18];
    const void* cls_b = d_in[19];

    char* p = (char*)d_ws;
    auto alloc = [&](size_t bytes) -> char* {
        char* r = p; p += (bytes + 255) & ~(size_t)255; return r;
    };
    float* x      = (float*)alloc(6291456ull * 4);    // residual (B*S*D) fp32       25.2MB
    u16*   h      = (u16*)  alloc(6291456ull * 2);    // LN out / attout (shared)    12.6MB
    u16*   qkvB   = (u16*)  alloc(18874368ull * 2);   // qkv bf16 (B*S*2304)         37.7MB
    u16*   vt     = (u16*)  alloc(6291456ull * 2);    // V^T (96,64,1024)            12.6MB
    u16*   ffmid  = (u16*)  alloc(25165824ull * 2);   // (8192,3072) bf16            50.3MB
    u16*   wqkvT  = (u16*)  alloc(1769472ull * 2);    // (2304,768) one layer
    u16*   woutT  = (u16*)  alloc(589824ull * 2);     // (768,768)
    u16*   wff1T  = (u16*)  alloc(2359296ull * 2);    // (3072,768)
    u16*   wff2T  = (u16*)  alloc(2359296ull * 2);    // (768,3072)
    float* params = (float*)alloc(62978ull * 4);      // converted fp32 param vectors
    int*   flag   = (int*)  alloc(256);
    u16*   attout = h;                                 // aliases h (disjoint lifetime)

    float* P_qkv_b = params + 0;
    float* P_out_b = params + 13824;
    float* P_n1_s  = params + 18432;
    float* P_n1_b  = params + 23040;
    float* P_ff1_b = params + 27648;
    float* P_ff2_b = params + 46080;
    float* P_n2_s  = params + 50688;
    float* P_n2_b  = params + 55296;
    float* P_hln_s = params + 59904;
    float* P_hln_b = params + 60672;
    float* P_cls_w = params + 61440;
    float* P_cls_b = params + 62976;

    detect_kernel<<<1, 256, 0, stream>>>(tok, flag);

    auto cvt = [&](const void* src, float* dst, int n) {
        to_f32_kernel<<<(n + 255) / 256, 256, 0, stream>>>(src, dst, n, flag);
    };
    cvt(qkv_b, P_qkv_b, 13824);  cvt(out_b, P_out_b, 4608);
    cvt(n1_s,  P_n1_s,  4608);   cvt(n1_b,  P_n1_b,  4608);
    cvt(ff1_b, P_ff1_b, 18432);  cvt(ff2_b, P_ff2_b, 4608);
    cvt(n2_s,  P_n2_s,  4608);   cvt(n2_b,  P_n2_b,  4608);
    cvt(hln_s, P_hln_s, 768);    cvt(hln_b, P_hln_b, 768);
    cvt(cls_w, P_cls_w, 1536);   cvt(cls_b, P_cls_b, 2);

    embed_kernel<<<6144, 256, 0, stream>>>(ids, tok, pos, x, flag);

    for (int l = 0; l < 6; ++l) {
        transpose_w_kernel<<<dim3(72, 24), 256, 0, stream>>>(qkv_w, (size_t)l * 1769472, wqkvT, 768, 2304, flag);
        transpose_w_kernel<<<dim3(24, 24), 256, 0, stream>>>(out_w, (size_t)l * 589824,  woutT, 768, 768,  flag);
        transpose_w_kernel<<<dim3(96, 24), 256, 0, stream>>>(ff1_w, (size_t)l * 2359296, wff1T, 768, 3072, flag);
        transpose_w_kernel<<<dim3(24, 96), 256, 0, stream>>>(ff2_w, (size_t)l * 2359296, wff2T, 3072, 768, flag);

        layernorm_kernel<<<8192, 256, 0, stream>>>(x, P_n1_s + l * 768, P_n1_b + l * 768, h);
        gemm_std<0><<<dim3(18, 64), 256, 0, stream>>>(h, 768, wqkvT, 768,
                                                      P_qkv_b + l * 2304, qkvB, 2304, 768);
        build_vt_kernel<<<dim3(16, 96), 256, 0, stream>>>(qkvB, vt);
        flash_attn<<<dim3(8, 96), 256, 0, stream>>>(qkvB, vt, mask, attout);
        gemm_splitk<<<dim3(6, 64, 2), 256, 0, stream>>>(attout, 768, woutT, 768,
                                                        P_out_b + l * 768, x, 768, 384);
        layernorm_kernel<<<8192, 256, 0, stream>>>(x, P_n2_s + l * 768, P_n2_b + l * 768, h);
        gemm_std<1><<<dim3(24, 64), 256, 0, stream>>>(h, 768, wff1T, 768,
                                                      P_ff1_b + l * 3072, ffmid, 3072, 768);
        // ff2: split-2 (split-4's atomic traffic/contention was net-negative)
        gemm_splitk<<<dim3(6, 64, 2), 256, 0, stream>>>(ffmid, 3072, wff2T, 3072,
                                                        P_ff2_b + l * 768, x, 768, 1536);
    }
    pooled_cls_kernel<<<8, 256, 0, stream>>>(x, P_hln_s, P_hln_b, P_cls_w, P_cls_b, d_out, flag);
}

// Round 5
// 2173.942 us; speedup vs baseline: 1.1867x; 1.0959x over previous
//
#include <hip/hip_runtime.h>
#include <hip/hip_bf16.h>

typedef unsigned short u16;
typedef __bf16 bf16x8 __attribute__((ext_vector_type(8)));
typedef float f32x4 __attribute__((ext_vector_type(4)));
typedef unsigned int u32x4 __attribute__((ext_vector_type(4)));

#define DEVI __device__ __forceinline__

typedef __attribute__((address_space(3))) void lds_void;
typedef __attribute__((address_space(1))) const void gbl_void;

// async global->LDS, 16B per lane (global_load_lds_dwordx4)
DEVI void gload16(const void* gp, void* lp) {
    __builtin_amdgcn_global_load_lds((gbl_void*)gp, (lds_void*)lp, 16, 0, 0);
}

// fp32 -> bf16 round-to-nearest-even
DEVI u16 f2b(float f) {
    unsigned int u = __builtin_bit_cast(unsigned int, f);
    unsigned int lsb = (u >> 16) & 1u;
    u += 0x7fffu + lsb;
    return (u16)(u >> 16);
}
DEVI float b2f(u16 b) {
    unsigned int u = ((unsigned int)b) << 16;
    return __builtin_bit_cast(float, u);
}

// native exp2 (v_exp_f32)
DEVI float fexp2(float x) {
#if __has_builtin(__builtin_amdgcn_exp2f)
    return __builtin_amdgcn_exp2f(x);
#else
    return __expf(x * 0.6931471805599453f);
#endif
}

// XCD-chunk swizzle (T1), 2D-only + z-passthrough. Hardware round-robins
// consecutive blocks over 8 XCDs; remap (bx,by) so each XCD gets a
// CONTIGUOUS chunk of 2D tile ids -> blocks sharing an A row-panel hit the
// same XCD L2. z (split-K index) passed through RAW (round-3 lesson:
// folding z into the chunk id put z-splits on different XCDs concurrently).
// Bijective iff (gx*gy)%8==0 (all our GEMM grids); else identity.
DEVI void swz_block(int& bx, int& by, int& bz) {
    const int gx = gridDim.x, gy = gridDim.y;
    const int nwg2 = gx * gy;
    int hw = blockIdx.x + gx * blockIdx.y;
    int id = (nwg2 & 7) ? hw : ((hw & 7) * (nwg2 >> 3) + (hw >> 3));
    bx = id % gx;
    by = id / gx;
    bz = blockIdx.z;
}

DEVI float blockReduceSum(float v, float* red, int tid) {
    #pragma unroll
    for (int o = 32; o; o >>= 1) v += __shfl_xor(v, o);
    __syncthreads();
    if ((tid & 63) == 0) red[tid >> 6] = v;
    __syncthreads();
    return red[0] + red[1] + red[2] + red[3];
}

// ---------------------------------------------------------------------------
// Detect input dtype: flag=1 if float inputs are bf16, 0 if fp32.
// ---------------------------------------------------------------------------
__global__ void detect_kernel(const void* tok, int* flag) {
    __shared__ int bad;
    if (threadIdx.x == 0) bad = 0;
    __syncthreads();
    const u16* p = (const u16*)tok;
    int cnt = 0;
    for (int j = 0; j < 16; ++j) {
        float v = b2f(p[2 * (threadIdx.x * 16 + j)]);
        if (!(fabsf(v) < 1.0f)) cnt++;
    }
    if (cnt) atomicAdd(&bad, 1);
    __syncthreads();
    if (threadIdx.x == 0) flag[0] = (bad == 0) ? 1 : 0;
}

__global__ void to_f32_kernel(const void* src, float* dst, int n, const int* flag) {
    int i = blockIdx.x * 256 + threadIdx.x;
    if (i >= n) return;
    if (flag[0]) dst[i] = b2f(((const u16*)src)[i]);
    else         dst[i] = ((const float*)src)[i];
}

// ---------------------------------------------------------------------------
// Core bf16 GEMM, async staging (m97 pattern): C(128,128) += A @ Bt^T.
// BK=32; 256 threads; per K-iter each wave issues 2 A- and 2 B-
// global_load_lds_dwordx4 (wave-uniform LDS base + lane*16B, packed rows of
// 32 u16). K % 32 == 0; rows 16B-aligned.
// ---------------------------------------------------------------------------
DEVI void gemm_core_async(const u16* __restrict__ A, int lda,
                          const u16* __restrict__ Bt, int ldb,
                          int K, f32x4 (&acc)[4][4],
                          u16* As, u16* Bs)
{
    const int tid  = threadIdx.x;
    const int lane = tid & 63;
    const int wave = tid >> 6;
    const int quad = lane >> 4;
    const int l16  = lane & 15;
    const int wm   = wave >> 1;
    const int wn   = wave & 1;

    // chunk indices this wave stages: instr i covers chunks (wave*2+i)*64+lane
    const int c0 = (wave * 2 + 0) * 64 + lane;
    const int c1 = (wave * 2 + 1) * 64 + lane;
    const int r0 = c0 >> 2, h0 = (c0 & 3) * 8;
    const int r1 = c1 >> 2, h1 = (c1 & 3) * 8;

    for (int k0 = 0; k0 < K; k0 += 32) {
        __syncthreads();   // prior iter's LDS reads drained before overwrite
        gload16(A  + (size_t)r0 * lda + k0 + h0, As + c0 * 8);
        gload16(Bt + (size_t)r0 * ldb + k0 + h0, Bs + c0 * 8);
        gload16(A  + (size_t)r1 * lda + k0 + h1, As + c1 * 8);
        gload16(Bt + (size_t)r1 * ldb + k0 + h1, Bs + c1 * 8);
        __syncthreads();   // compiler inserts vmcnt(0) drain before barrier

        bf16x8 af[4], bfv[4];
        #pragma unroll
        for (int mt = 0; mt < 4; ++mt)
            af[mt] = *(const bf16x8*)(As + (wm * 64 + mt * 16 + l16) * 32 + quad * 8);
        #pragma unroll
        for (int nt = 0; nt < 4; ++nt)
            bfv[nt] = *(const bf16x8*)(Bs + (wn * 64 + nt * 16 + l16) * 32 + quad * 8);
        #pragma unroll
        for (int mt = 0; mt < 4; ++mt)
            #pragma unroll
            for (int nt = 0; nt < 4; ++nt)
                acc[mt][nt] = __builtin_amdgcn_mfma_f32_16x16x32_bf16(af[mt], bfv[nt], acc[mt][nt], 0, 0, 0);
    }
}

// EPI: 0 = bf16 out (+bias), 1 = bf16 relu (+bias)
template<int EPI>
__global__ __launch_bounds__(256) void gemm_std(
    const u16* __restrict__ A, int lda,
    const u16* __restrict__ Bt, int ldb,
    const float* __restrict__ bias,
    u16* __restrict__ outB, int ldc, int K)
{
    __shared__ u16 As[128 * 32];
    __shared__ u16 Bs[128 * 32];
    int bx, by, bz;
    swz_block(bx, by, bz);
    const size_t bM = (size_t)by * 128;
    const size_t bN = (size_t)bx * 128;
    f32x4 acc[4][4] = {};
    gemm_core_async(A + bM * lda, lda, Bt + bN * ldb, ldb, K, acc, As, Bs);

    const int tid = threadIdx.x, lane = tid & 63, wave = tid >> 6;
    const int wm = wave >> 1, wn = wave & 1, quad = lane >> 4, l16 = lane & 15;
    #pragma unroll
    for (int mt = 0; mt < 4; ++mt)
        #pragma unroll
        for (int nt = 0; nt < 4; ++nt) {
            size_t col = bN + wn * 64 + nt * 16 + l16;
            float bcol = bias[col];
            #pragma unroll
            for (int r = 0; r < 4; ++r) {
                size_t row = bM + wm * 64 + mt * 16 + quad * 4 + r;
                float v = acc[mt][nt][r] + bcol;
                if constexpr (EPI == 1) v = fmaxf(v, 0.f);
                outB[row * ldc + col] = f2b(v);
            }
        }
}

// Split-K GEMM writing fp32 PARTIALS with plain stores (no atomics).
// part[z] is a full (M,ldc) fp32 buffer at part + z*pstride.
// bias folded into split 0. Reduction x += P0+P1 is fused into the next
// layernorm (round-4 lesson: 12.6M fp32 atomic RMW/dispatch was flooding
// the XCD L2 RMW path and backpressuring co-resident blocks' staging).
__global__ __launch_bounds__(256) void gemm_partial(
    const u16* __restrict__ A, int lda,
    const u16* __restrict__ Bt, int ldb,
    const float* __restrict__ bias,
    float* __restrict__ part, size_t pstride, int ldc, int Ksub)
{
    __shared__ u16 As[128 * 32];
    __shared__ u16 Bs[128 * 32];
    int bx, by, bz;
    swz_block(bx, by, bz);
    const size_t bM = (size_t)by * 128;
    const size_t bN = (size_t)bx * 128;
    const int Koff = bz * Ksub;
    f32x4 acc[4][4] = {};
    gemm_core_async(A + bM * lda + Koff, lda, Bt + bN * ldb + Koff, ldb, Ksub, acc, As, Bs);

    float* __restrict__ P = part + (size_t)bz * pstride;
    const int tid = threadIdx.x, lane = tid & 63, wave = tid >> 6;
    const int wm = wave >> 1, wn = wave & 1, quad = lane >> 4, l16 = lane & 15;
    const bool addb = (bz == 0);
    #pragma unroll
    for (int mt = 0; mt < 4; ++mt)
        #pragma unroll
        for (int nt = 0; nt < 4; ++nt) {
            size_t col = bN + wn * 64 + nt * 16 + l16;
            float bcol = addb ? bias[col] : 0.f;
            #pragma unroll
            for (int r = 0; r < 4; ++r) {
                size_t row = bM + wm * 64 + mt * 16 + quad * 4 + r;
                P[row * ldc + col] = acc[mt][nt][r] + bcol;
            }
        }
}

// ---------------------------------------------------------------------------
// Flash attention: one block = one (b,h) x 128 q-rows. 256 thr (4 waves).
// LDS = 51200B -> 3 blocks/CU by LDS (grid is exactly 3 blocks/CU, one
// balanced residency round). Launch bounds (256,2): (256,3) forced the
// allocator below the live set -> 84 VGPR + scratch spill, 2x slower.
// All tiles XOR-swizzled at 16B-slot granularity (slot ^= row&7).
// P round-trips LDS in two 64-key halves (wave-private rows, no barrier).
// Softmax in exp2 domain with additive bf16 mask bias folded via fma.
// ---------------------------------------------------------------------------
__global__ __launch_bounds__(256, 2) void flash_attn(
    const u16* __restrict__ qkv, const u16* __restrict__ vt,
    const int* __restrict__ mask, u16* __restrict__ attout)
{
    __shared__ u16 Ks[128 * 64];    // [key][d]   128B rows, swizzled   16KB
    __shared__ u16 Vs[64 * 128];    // [d][key]   256B rows, swizzled   16KB
    __shared__ u16 Ps[128 * 64];    // [q][key-half] 128B rows, swizzled 16KB
    __shared__ u16 Msb[1024];       // additive bias bf16: masked -> -1e9, else 0

    const int bh = blockIdx.y;
    const int b = bh / 12, h = bh % 12;
    const int q0 = blockIdx.x * 128;
    const int tid = threadIdx.x, lane = tid & 63, wave = tid >> 6;
    const int quad = lane >> 4, l16 = lane & 15;
    const int sw = l16 & 7;         // read-side swizzle key (row&7 == l16&7)

    for (int i = tid; i < 1024; i += 256)
        Msb[i] = (mask[b * 1024 + i] != 0) ? f2b(-1e9f) : (u16)0;

    bf16x8 aq[2][2];
    #pragma unroll
    for (int mt = 0; mt < 2; ++mt)
        #pragma unroll
        for (int s = 0; s < 2; ++s)
            aq[mt][s] = *(const bf16x8*)(qkv + (size_t)(b * 1024 + q0 + wave * 32 + mt * 16 + l16) * 2304
                                          + h * 192 + s * 32 + quad * 8);

    const float SC2 = 0.18033688011112042f;   // 0.125 * log2(e): softmax in exp2 domain

    float mi[2][4], li[2][4];
    f32x4 Oacc[2][4] = {};
    #pragma unroll
    for (int mt = 0; mt < 2; ++mt)
        #pragma unroll
        for (int r = 0; r < 4; ++r) { mi[mt][r] = -3e38f; li[mt][r] = 0.f; }

    for (int kt = 0; kt < 8; ++kt) {
        u32x4 kreg[4], vreg[4];
        #pragma unroll
        for (int i = 0; i < 4; ++i) {
            int id = i * 256 + tid, row = id >> 3, ch = id & 7;
            kreg[i] = *(const u32x4*)(qkv + (size_t)(b * 1024 + kt * 128 + row) * 2304 + h * 192 + 64 + ch * 8);
        }
        #pragma unroll
        for (int i = 0; i < 4; ++i) {
            int id = i * 256 + tid, row = id >> 4, ch = id & 15;
            vreg[i] = *(const u32x4*)(vt + (size_t)bh * 65536 + (size_t)row * 1024 + kt * 128 + ch * 8);
        }
        __syncthreads();
        #pragma unroll
        for (int i = 0; i < 4; ++i) {
            int id = i * 256 + tid, row = id >> 3, ch = id & 7;
            *(u32x4*)(Ks + row * 64 + ((ch ^ (row & 7)) * 8)) = kreg[i];
        }
        #pragma unroll
        for (int i = 0; i < 4; ++i) {
            int id = i * 256 + tid, row = id >> 4, ch = id & 15;
            *(u32x4*)(Vs + row * 128 + ((ch ^ (row & 7)) * 8)) = vreg[i];
        }
        __syncthreads();

        f32x4 Sacc[2][8] = {};
        #pragma unroll
        for (int s = 0; s < 2; ++s) {
            bf16x8 kf[8];
            #pragma unroll
            for (int nt = 0; nt < 8; ++nt)
                kf[nt] = *(const bf16x8*)(Ks + (nt * 16 + l16) * 64 + (((s * 4 + quad) ^ sw) * 8));
            #pragma unroll
            for (int mt = 0; mt < 2; ++mt)
                #pragma unroll
                for (int nt = 0; nt < 8; ++nt)
                    Sacc[mt][nt] = __builtin_amdgcn_mfma_f32_16x16x32_bf16(aq[mt][s], kf[nt], Sacc[mt][nt], 0, 0, 0);
        }

        // scale (exp2 domain) + additive mask bias in one fma per element
        float bias[8];
        #pragma unroll
        for (int nt = 0; nt < 8; ++nt) bias[nt] = b2f(Msb[kt * 128 + nt * 16 + l16]);
        #pragma unroll
        for (int mt = 0; mt < 2; ++mt)
            #pragma unroll
            for (int nt = 0; nt < 8; ++nt)
                #pragma unroll
                for (int r = 0; r < 4; ++r)
                    Sacc[mt][nt][r] = fmaf(Sacc[mt][nt][r], SC2, bias[nt]);

        #pragma unroll
        for (int mt = 0; mt < 2; ++mt) {
            float al[4];
            #pragma unroll
            for (int r = 0; r < 4; ++r) {
                float rm = fmaxf(
                    fmaxf(fmaxf(Sacc[mt][0][r], Sacc[mt][1][r]), fmaxf(Sacc[mt][2][r], Sacc[mt][3][r])),
                    fmaxf(fmaxf(Sacc[mt][4][r], Sacc[mt][5][r]), fmaxf(Sacc[mt][6][r], Sacc[mt][7][r])));
                #pragma unroll
                for (int o = 8; o; o >>= 1) rm = fmaxf(rm, __shfl_xor(rm, o));
                float mn = fmaxf(mi[mt][r], rm);
                al[r] = fexp2(mi[mt][r] - mn);
                mi[mt][r] = mn;
                float rs = 0.f;
                #pragma unroll
                for (int nt = 0; nt < 8; ++nt) {
                    float pv = fexp2(Sacc[mt][nt][r] - mn);
                    rs += pv;
                    Sacc[mt][nt][r] = pv;
                }
                #pragma unroll
                for (int o = 8; o; o >>= 1) rs += __shfl_xor(rs, o);
                li[mt][r] = li[mt][r] * al[r] + rs;
            }
            #pragma unroll
            for (int ntv = 0; ntv < 4; ++ntv)
                #pragma unroll
                for (int r = 0; r < 4; ++r) Oacc[mt][ntv][r] *= al[r];
        }

        // P -> LDS -> PV in two 64-key halves (wave-private rows; DS in-order
        // per wave + compiler aliasing keeps write-after-read correct)
        #pragma unroll
        for (int hf = 0; hf < 2; ++hf) {
            #pragma unroll
            for (int mt = 0; mt < 2; ++mt) {
                const int rowb = wave * 32 + mt * 16 + quad * 4;
                #pragma unroll
                for (int n4 = 0; n4 < 4; ++n4) {
                    const int slot = n4 * 2 + (l16 >> 3);
                    #pragma unroll
                    for (int r = 0; r < 4; ++r) {
                        const int row = rowb + r;
                        Ps[row * 64 + ((slot ^ (row & 7)) * 8) + sw] = f2b(Sacc[mt][hf * 4 + n4][r]);
                    }
                }
            }
            #pragma unroll
            for (int s2h = 0; s2h < 2; ++s2h) {
                const int s2 = hf * 2 + s2h;
                bf16x8 vf[4];
                #pragma unroll
                for (int ntv = 0; ntv < 4; ++ntv)
                    vf[ntv] = *(const bf16x8*)(Vs + (ntv * 16 + l16) * 128 + (((s2 * 4 + quad) ^ sw) * 8));
                #pragma unroll
                for (int mt2 = 0; mt2 < 2; ++mt2) {
                    bf16x8 pf = *(const bf16x8*)(Ps + (wave * 32 + mt2 * 16 + l16) * 64 + (((s2h * 4 + quad) ^ sw) * 8));
                    #pragma unroll
                    for (int ntv = 0; ntv < 4; ++ntv)
                        Oacc[mt2][ntv] = __builtin_amdgcn_mfma_f32_16x16x32_bf16(pf, vf[ntv], Oacc[mt2][ntv], 0, 0, 0);
                }
            }
        }
    }

    #pragma unroll
    for (int mt = 0; mt < 2; ++mt)
        #pragma unroll
        for (int r = 0; r < 4; ++r) {
            float inv = 1.0f / li[mt][r];
            int s = q0 + wave * 32 + mt * 16 + quad * 4 + r;
            #pragma unroll
            for (int ntv = 0; ntv < 4; ++ntv)
                attout[((size_t)(b * 1024 + s)) * 768 + h * 64 + ntv * 16 + l16] = f2b(Oacc[mt][ntv][r] * inv);
        }
}

// x[b,s,:] = (token_emb[id] + pos_emb[s]) * sqrt(768)  (dual dtype)
__global__ __launch_bounds__(256) void embed_kernel(
    const int* __restrict__ ids, const void* __restrict__ tok,
    const void* __restrict__ pos, float* __restrict__ x, const int* __restrict__ flag)
{
    const int e  = blockIdx.x * 256 + threadIdx.x;
    const int bs = e / 192;
    const int d  = (e - bs * 192) * 4;
    const int s  = bs & 1023;
    const int id = ids[bs];
    float t[4], p4[4];
    if (flag[0]) {
        const u16* tb = (const u16*)tok + (size_t)id * 768 + d;
        const u16* pb = (const u16*)pos + (size_t)s  * 768 + d;
        #pragma unroll
        for (int j = 0; j < 4; ++j) { t[j] = b2f(tb[j]); p4[j] = b2f(pb[j]); }
    } else {
        const float* tb = (const float*)tok + (size_t)id * 768 + d;
        const float* pb = (const float*)pos + (size_t)s  * 768 + d;
        #pragma unroll
        for (int j = 0; j < 4; ++j) { t[j] = tb[j]; p4[j] = pb[j]; }
    }
    float* xo = x + (size_t)bs * 768 + d;
    #pragma unroll
    for (int j = 0; j < 4; ++j) xo[j] = (t[j] + p4[j]) * 27.7128129211020f;
}

// LayerNorm with optional split-K partial fold: if part != nullptr,
// x[row] += part0[row] + part1[row] (written back: x is the residual),
// then LN(x[row]) -> out. part1 = part + 6291456 elements.
__global__ __launch_bounds__(256) void layernorm_kernel(
    float* __restrict__ x, const float* __restrict__ part,
    const float* __restrict__ sc, const float* __restrict__ bi,
    u16* __restrict__ out)
{
    __shared__ float red[4];
    const size_t row = blockIdx.x;
    float* xr = x + row * 768;
    const int tid = threadIdx.x;
    float v0 = xr[tid], v1 = xr[tid + 256], v2 = xr[tid + 512];
    if (part) {
        const float* p0 = part + row * 768;
        const float* p1 = p0 + 6291456;
        v0 += p0[tid]       + p1[tid];
        v1 += p0[tid + 256] + p1[tid + 256];
        v2 += p0[tid + 512] + p1[tid + 512];
        xr[tid] = v0; xr[tid + 256] = v1; xr[tid + 512] = v2;
    }
    float s = blockReduceSum(v0 + v1 + v2, red, tid);
    float mean = s * (1.0f / 768.0f);
    float d0 = v0 - mean, d1 = v1 - mean, d2 = v2 - mean;
    float q = blockReduceSum(d0 * d0 + d1 * d1 + d2 * d2, red, tid);
    float rstd = rsqrtf(q * (1.0f / 768.0f) + 1e-5f);
    u16* orow = out + row * 768;
    orow[tid]       = f2b(d0 * rstd * sc[tid]       + bi[tid]);
    orow[tid + 256] = f2b(d1 * rstd * sc[tid + 256] + bi[tid + 256]);
    orow[tid + 512] = f2b(d2 * rstd * sc[tid + 512] + bi[tid + 512]);
}

// W (Kd,Nd) [fp32 or bf16 per flag] -> Wt (Nd,Kd) bf16; one layer per launch
__global__ __launch_bounds__(256) void transpose_w_kernel(
    const void* __restrict__ W, size_t off, u16* __restrict__ Wt,
    int Kd, int Nd, const int* __restrict__ flag)
{
    __shared__ u16 tile[32][34];
    const int n0 = blockIdx.x * 32, k0 = blockIdx.y * 32;
    const int tx = threadIdx.x & 31, ty = threadIdx.x >> 5;
    const int fl = flag[0];
    #pragma unroll
    for (int i = 0; i < 4; ++i) {
        size_t idx = off + (size_t)(k0 + ty + i * 8) * Nd + n0 + tx;
        u16 val = fl ? ((const u16*)W)[idx] : f2b(((const float*)W)[idx]);
        tile[ty + i * 8][tx] = val;
    }
    __syncthreads();
    #pragma unroll
    for (int i = 0; i < 4; ++i)
        Wt[(size_t)(n0 + ty + i * 8) * Kd + k0 + tx] = tile[tx][ty + i * 8];
}

// vt[bh, d, t] = qkv[b, t, h*192+128+d]
__global__ __launch_bounds__(256) void build_vt_kernel(
    const u16* __restrict__ qkv, u16* __restrict__ vt)
{
    __shared__ u16 tile[64][72];
    const int bh = blockIdx.y;
    const int b = bh / 12, h = bh % 12;
    const int t0 = blockIdx.x * 64;
    const int tid = threadIdx.x;
    const int tl = tid >> 2;
    const int d4 = (tid & 3) * 16;
    const u16* src = qkv + (size_t)(b * 1024 + t0 + tl) * 2304 + h * 192 + 128 + d4;
    *(u32x4*)(&tile[tl][d4])     = *(const u32x4*)(src);
    *(u32x4*)(&tile[tl][d4 + 8]) = *(const u32x4*)(src + 8);
    __syncthreads();
    const int dd = tid >> 2;
    const int tstart = (tid & 3) * 16;
    union { u16 us[16]; u32x4 v[2]; } pk;
    #pragma unroll
    for (int j = 0; j < 16; ++j) pk.us[j] = tile[tstart + j][dd];
    u16* dst = vt + ((size_t)bh * 64 + dd) * 1024 + t0 + tstart;
    *(u32x4*)(dst)     = pk.v[0];
    *(u32x4*)(dst + 8) = pk.v[1];
}

// pooled = LN(x[:,0,:] + F0 + F1); out = pooled @ cls_w + cls_b
// (folds the final ff2 partials at row (b,0) only — rest of x is dead)
__global__ __launch_bounds__(256) void pooled_cls_kernel(
    const float* __restrict__ x, const float* __restrict__ part,
    const float* __restrict__ hs, const float* __restrict__ hb,
    const float* __restrict__ cw, const float* __restrict__ cb, void* __restrict__ dout,
    const int* __restrict__ flag)
{
    __shared__ float red[4];
    __shared__ float pooled[768];
    const int b = blockIdx.x;
    const float* xr = x + (size_t)b * 1024 * 768;
    const float* p0 = part + (size_t)b * 1024 * 768;
    const float* p1 = p0 + 6291456;
    const int tid = threadIdx.x;
    float v0 = xr[tid]       + p0[tid]       + p1[tid];
    float v1 = xr[tid + 256] + p0[tid + 256] + p1[tid + 256];
    float v2 = xr[tid + 512] + p0[tid + 512] + p1[tid + 512];
    float s = blockReduceSum(v0 + v1 + v2, red, tid);
    float mean = s * (1.0f / 768.0f);
    float d0 = v0 - mean, d1 = v1 - mean, d2 = v2 - mean;
    float q = blockReduceSum(d0 * d0 + d1 * d1 + d2 * d2, red, tid);
    float rstd = rsqrtf(q * (1.0f / 768.0f) + 1e-5f);
    pooled[tid]       = d0 * rstd * hs[tid]       + hb[tid];
    pooled[tid + 256] = d1 * rstd * hs[tid + 256] + hb[tid + 256];
    pooled[tid + 512] = d2 * rstd * hs[tid + 512] + hb[tid + 512];
    __syncthreads();
    float q0 = 0.f, q1 = 0.f;
    for (int c = tid; c < 768; c += 256) {
        float pv = pooled[c];
        q0 += pv * cw[2 * c];
        q1 += pv * cw[2 * c + 1];
    }
    q0 = blockReduceSum(q0, red, tid);
    q1 = blockReduceSum(q1, red, tid);
    if (tid == 0) {
        float o0 = q0 + cb[0], o1 = q1 + cb[1];
        if (flag[0]) {
            ((u16*)dout)[b * 2 + 0] = f2b(o0);
            ((u16*)dout)[b * 2 + 1] = f2b(o1);
        } else {
            ((float*)dout)[b * 2 + 0] = o0;
            ((float*)dout)[b * 2 + 1] = o1;
        }
    }
}

extern "C" void kernel_launch(void* const* d_in, const int* in_sizes, int n_in,
                              void* d_out, int out_size, void* d_ws, size_t ws_size,
                              hipStream_t stream)
{
    const int* ids  = (const int*)d_in[0];
    const int* mask = (const int*)d_in[1];
    const void* tok   = d_in[2];
    const void* pos   = d_in[3];
    const void* qkv_w = d_in[4];
    const void* qkv_b = d_in[5];
    const void* out_w = d_in[6];
    const void* out_b = d_in[7];
    const void* n1_s  = d_in[8];
    const void* n1_b  = d_in[9];
    const void* ff1_w = d_in[10];
    const void* ff1_b = d_in[11];
    const void* ff2_w = d_in[12];
    const void* ff2_b = d_in[13];
    const void* n2_s  = d_in[14];
    const void* n2_b  = d_in[15];
    const void* hln_s = d_in[16];
    const void* hln_b = d_in[17];
    const void* cls_w = d_in[18];
    const void* cls_b = d_in[19];

    char* p = (char*)d_ws;
    auto alloc = [&](size_t bytes) -> char* {
        char* r = p; p += (bytes + 255) & ~(size_t)255; return r;
    };
    float* x      = (float*)alloc(6291456ull * 4);    // residual (B*S*D) fp32       25.2MB
    u16*   h      = (u16*)  alloc(6291456ull * 2);    // LN out / attout (shared)    12.6MB
    u16*   qkvB   = (u16*)  alloc(18874368ull * 2);   // qkv bf16 (B*S*2304)         37.7MB
    u16*   vt     = (u16*)  alloc(6291456ull * 2);    // V^T (96,64,1024)            12.6MB
    u16*   ffmid  = (u16*)  alloc(25165824ull * 2);   // (8192,3072) bf16            50.3MB
    u16*   wqkvT  = (u16*)  alloc(1769472ull * 2);    // (2304,768) one layer
    u16*   woutT  = (u16*)  alloc(589824ull * 2);     // (768,768)
    u16*   wff1T  = (u16*)  alloc(2359296ull * 2);    // (3072,768)
    u16*   wff2T  = (u16*)  alloc(2359296ull * 2);    // (768,3072)
    float* params = (float*)alloc(62978ull * 4);      // converted fp32 param vectors
    int*   flag   = (int*)  alloc(256);
    u16*   attout = h;                                 // aliases h (disjoint lifetime)

    // Split-K partial buffers (each 2 x 6291456 fp32 = 50.33MB), recycled
    // from dead regions (no new workspace):
    //  - attn-out partials -> ffmid region (dead between attn-out and ff1)
    //  - ff2 partials      -> qkvB+vt region (dead after flash_attn; sizes
    //    37748736+12582912 = 50331648B, contiguous by alloc order)
    float* Apart = (float*)ffmid;
    float* Fpart = (float*)qkvB;

    float* P_qkv_b = params + 0;
    float* P_out_b = params + 13824;
    float* P_n1_s  = params + 18432;
    float* P_n1_b  = params + 23040;
    float* P_ff1_b = params + 27648;
    float* P_ff2_b = params + 46080;
    float* P_n2_s  = params + 50688;
    float* P_n2_b  = params + 55296;
    float* P_hln_s = params + 59904;
    float* P_hln_b = params + 60672;
    float* P_cls_w = params + 61440;
    float* P_cls_b = params + 62976;

    detect_kernel<<<1, 256, 0, stream>>>(tok, flag);

    auto cvt = [&](const void* src, float* dst, int n) {
        to_f32_kernel<<<(n + 255) / 256, 256, 0, stream>>>(src, dst, n, flag);
    };
    cvt(qkv_b, P_qkv_b, 13824);  cvt(out_b, P_out_b, 4608);
    cvt(n1_s,  P_n1_s,  4608);   cvt(n1_b,  P_n1_b,  4608);
    cvt(ff1_b, P_ff1_b, 18432);  cvt(ff2_b, P_ff2_b, 4608);
    cvt(n2_s,  P_n2_s,  4608);   cvt(n2_b,  P_n2_b,  4608);
    cvt(hln_s, P_hln_s, 768);    cvt(hln_b, P_hln_b, 768);
    cvt(cls_w, P_cls_w, 1536);   cvt(cls_b, P_cls_b, 2);

    embed_kernel<<<6144, 256, 0, stream>>>(ids, tok, pos, x, flag);

    for (int l = 0; l < 6; ++l) {
        transpose_w_kernel<<<dim3(72, 24), 256, 0, stream>>>(qkv_w, (size_t)l * 1769472, wqkvT, 768, 2304, flag);
        transpose_w_kernel<<<dim3(24, 24), 256, 0, stream>>>(out_w, (size_t)l * 589824,  woutT, 768, 768,  flag);
        transpose_w_kernel<<<dim3(96, 24), 256, 0, stream>>>(ff1_w, (size_t)l * 2359296, wff1T, 768, 3072, flag);
        transpose_w_kernel<<<dim3(24, 96), 256, 0, stream>>>(ff2_w, (size_t)l * 2359296, wff2T, 3072, 768, flag);

        // ln1: fold previous layer's ff2 partials (l>0); writes x + h
        layernorm_kernel<<<8192, 256, 0, stream>>>(x, (l == 0) ? nullptr : Fpart,
                                                   P_n1_s + l * 768, P_n1_b + l * 768, h);
        gemm_std<0><<<dim3(18, 64), 256, 0, stream>>>(h, 768, wqkvT, 768,
                                                      P_qkv_b + l * 2304, qkvB, 2304, 768);
        build_vt_kernel<<<dim3(16, 96), 256, 0, stream>>>(qkvB, vt);
        flash_attn<<<dim3(8, 96), 256, 0, stream>>>(qkvB, vt, mask, attout);
        // attn-out: partials into ffmid region (plain stores, no atomics)
        gemm_partial<<<dim3(6, 64, 2), 256, 0, stream>>>(attout, 768, woutT, 768,
                                                         P_out_b + l * 768, Apart, 6291456, 768, 384);
        // ln2: fold attn-out partials; writes x + h
        layernorm_kernel<<<8192, 256, 0, stream>>>(x, Apart,
                                                   P_n2_s + l * 768, P_n2_b + l * 768, h);
        gemm_std<1><<<dim3(24, 64), 256, 0, stream>>>(h, 768, wff1T, 768,
                                                      P_ff1_b + l * 3072, ffmid, 3072, 768);
        // ff2: partials into qkvB+vt region (folded by next ln1 / pooled)
        gemm_partial<<<dim3(6, 64, 2), 256, 0, stream>>>(ffmid, 3072, wff2T, 3072,
                                                         P_ff2_b + l * 768, Fpart, 6291456, 768, 1536);
    }
    pooled_cls_kernel<<<8, 256, 0, stream>>>(x, Fpart, P_hln_s, P_hln_b, P_cls_w, P_cls_b, d_out, flag);
}

// Round 6
// 2161.394 us; speedup vs baseline: 1.1936x; 1.0058x over previous
//
#include <hip/hip_runtime.h>
#include <hip/hip_bf16.h>

typedef unsigned short u16;
typedef __bf16 bf16x8 __attribute__((ext_vector_type(8)));
typedef float f32x4 __attribute__((ext_vector_type(4)));
typedef unsigned int u32x4 __attribute__((ext_vector_type(4)));

#define DEVI __device__ __forceinline__

typedef __attribute__((address_space(3))) void lds_void;
typedef __attribute__((address_space(1))) const void gbl_void;

// async global->LDS, 16B per lane (global_load_lds_dwordx4)
DEVI void gload16(const void* gp, void* lp) {
    __builtin_amdgcn_global_load_lds((gbl_void*)gp, (lds_void*)lp, 16, 0, 0);
}

// fp32 -> bf16 round-to-nearest-even
DEVI u16 f2b(float f) {
    unsigned int u = __builtin_bit_cast(unsigned int, f);
    unsigned int lsb = (u >> 16) & 1u;
    u += 0x7fffu + lsb;
    return (u16)(u >> 16);
}
DEVI float b2f(u16 b) {
    unsigned int u = ((unsigned int)b) << 16;
    return __builtin_bit_cast(float, u);
}

// native exp2 (v_exp_f32)
DEVI float fexp2(float x) {
#if __has_builtin(__builtin_amdgcn_exp2f)
    return __builtin_amdgcn_exp2f(x);
#else
    return __expf(x * 0.6931471805599453f);
#endif
}

// XCD-chunk swizzle (T1), 2D-only + z-passthrough. Hardware round-robins
// consecutive blocks over 8 XCDs; remap (bx,by) so each XCD gets a
// CONTIGUOUS chunk of 2D tile ids -> blocks sharing an A row-panel hit the
// same XCD L2. z (split-K index) passed through RAW (round-3 lesson:
// folding z into the chunk id put z-splits on different XCDs concurrently).
// Bijective iff (gx*gy)%8==0 (all our GEMM grids); else identity.
DEVI void swz_block(int& bx, int& by, int& bz) {
    const int gx = gridDim.x, gy = gridDim.y;
    const int nwg2 = gx * gy;
    int hw = blockIdx.x + gx * blockIdx.y;
    int id = (nwg2 & 7) ? hw : ((hw & 7) * (nwg2 >> 3) + (hw >> 3));
    bx = id % gx;
    by = id / gx;
    bz = blockIdx.z;
}

DEVI float blockReduceSum(float v, float* red, int tid) {
    #pragma unroll
    for (int o = 32; o; o >>= 1) v += __shfl_xor(v, o);
    __syncthreads();
    if ((tid & 63) == 0) red[tid >> 6] = v;
    __syncthreads();
    return red[0] + red[1] + red[2] + red[3];
}

// ---------------------------------------------------------------------------
// Detect input dtype: flag=1 if float inputs are bf16, 0 if fp32.
// ---------------------------------------------------------------------------
__global__ void detect_kernel(const void* tok, int* flag) {
    __shared__ int bad;
    if (threadIdx.x == 0) bad = 0;
    __syncthreads();
    const u16* p = (const u16*)tok;
    int cnt = 0;
    for (int j = 0; j < 16; ++j) {
        float v = b2f(p[2 * (threadIdx.x * 16 + j)]);
        if (!(fabsf(v) < 1.0f)) cnt++;
    }
    if (cnt) atomicAdd(&bad, 1);
    __syncthreads();
    if (threadIdx.x == 0) flag[0] = (bad == 0) ? 1 : 0;
}

__global__ void to_f32_kernel(const void* src, float* dst, int n, const int* flag) {
    int i = blockIdx.x * 256 + threadIdx.x;
    if (i >= n) return;
    if (flag[0]) dst[i] = b2f(((const u16*)src)[i]);
    else         dst[i] = ((const float*)src)[i];
}

// ---------------------------------------------------------------------------
// Core bf16 GEMM, async staging (m97 pattern): C(128,128) += A @ Bt^T.
// BK=32; 256 threads; per K-iter each wave issues 2 A- and 2 B-
// global_load_lds_dwordx4 (wave-uniform LDS base + lane*16B, packed rows of
// 32 u16). K % 32 == 0; rows 16B-aligned.
// ---------------------------------------------------------------------------
DEVI void gemm_core_async(const u16* __restrict__ A, int lda,
                          const u16* __restrict__ Bt, int ldb,
                          int K, f32x4 (&acc)[4][4],
                          u16* As, u16* Bs)
{
    const int tid  = threadIdx.x;
    const int lane = tid & 63;
    const int wave = tid >> 6;
    const int quad = lane >> 4;
    const int l16  = lane & 15;
    const int wm   = wave >> 1;
    const int wn   = wave & 1;

    // chunk indices this wave stages: instr i covers chunks (wave*2+i)*64+lane
    const int c0 = (wave * 2 + 0) * 64 + lane;
    const int c1 = (wave * 2 + 1) * 64 + lane;
    const int r0 = c0 >> 2, h0 = (c0 & 3) * 8;
    const int r1 = c1 >> 2, h1 = (c1 & 3) * 8;

    for (int k0 = 0; k0 < K; k0 += 32) {
        __syncthreads();   // prior iter's LDS reads drained before overwrite
        gload16(A  + (size_t)r0 * lda + k0 + h0, As + c0 * 8);
        gload16(Bt + (size_t)r0 * ldb + k0 + h0, Bs + c0 * 8);
        gload16(A  + (size_t)r1 * lda + k0 + h1, As + c1 * 8);
        gload16(Bt + (size_t)r1 * ldb + k0 + h1, Bs + c1 * 8);
        __syncthreads();   // compiler inserts vmcnt(0) drain before barrier

        bf16x8 af[4], bfv[4];
        #pragma unroll
        for (int mt = 0; mt < 4; ++mt)
            af[mt] = *(const bf16x8*)(As + (wm * 64 + mt * 16 + l16) * 32 + quad * 8);
        #pragma unroll
        for (int nt = 0; nt < 4; ++nt)
            bfv[nt] = *(const bf16x8*)(Bs + (wn * 64 + nt * 16 + l16) * 32 + quad * 8);
        #pragma unroll
        for (int mt = 0; mt < 4; ++mt)
            #pragma unroll
            for (int nt = 0; nt < 4; ++nt)
                acc[mt][nt] = __builtin_amdgcn_mfma_f32_16x16x32_bf16(af[mt], bfv[nt], acc[mt][nt], 0, 0, 0);
    }
}

// EPI: 0 = bf16 out (+bias), 1 = bf16 relu (+bias)
template<int EPI>
__global__ __launch_bounds__(256) void gemm_std(
    const u16* __restrict__ A, int lda,
    const u16* __restrict__ Bt, int ldb,
    const float* __restrict__ bias,
    u16* __restrict__ outB, int ldc, int K)
{
    __shared__ u16 As[128 * 32];
    __shared__ u16 Bs[128 * 32];
    int bx, by, bz;
    swz_block(bx, by, bz);
    const size_t bM = (size_t)by * 128;
    const size_t bN = (size_t)bx * 128;
    f32x4 acc[4][4] = {};
    gemm_core_async(A + bM * lda, lda, Bt + bN * ldb, ldb, K, acc, As, Bs);

    const int tid = threadIdx.x, lane = tid & 63, wave = tid >> 6;
    const int wm = wave >> 1, wn = wave & 1, quad = lane >> 4, l16 = lane & 15;
    #pragma unroll
    for (int mt = 0; mt < 4; ++mt)
        #pragma unroll
        for (int nt = 0; nt < 4; ++nt) {
            size_t col = bN + wn * 64 + nt * 16 + l16;
            float bcol = bias[col];
            #pragma unroll
            for (int r = 0; r < 4; ++r) {
                size_t row = bM + wm * 64 + mt * 16 + quad * 4 + r;
                float v = acc[mt][nt][r] + bcol;
                if constexpr (EPI == 1) v = fmaxf(v, 0.f);
                outB[row * ldc + col] = f2b(v);
            }
        }
}

// Split-K GEMM writing fp32 PARTIALS with plain stores (no atomics).
// part[z] is a full (M,ldc) fp32 buffer at part + z*pstride.
// bias folded into split 0. Reduction x += P0+P1 is fused into the next
// layernorm (round-4 lesson: 12.6M fp32 atomic RMW/dispatch was flooding
// the XCD L2 RMW path and backpressuring co-resident blocks' staging).
__global__ __launch_bounds__(256) void gemm_partial(
    const u16* __restrict__ A, int lda,
    const u16* __restrict__ Bt, int ldb,
    const float* __restrict__ bias,
    float* __restrict__ part, size_t pstride, int ldc, int Ksub)
{
    __shared__ u16 As[128 * 32];
    __shared__ u16 Bs[128 * 32];
    int bx, by, bz;
    swz_block(bx, by, bz);
    const size_t bM = (size_t)by * 128;
    const size_t bN = (size_t)bx * 128;
    const int Koff = bz * Ksub;
    f32x4 acc[4][4] = {};
    gemm_core_async(A + bM * lda + Koff, lda, Bt + bN * ldb + Koff, ldb, Ksub, acc, As, Bs);

    float* __restrict__ P = part + (size_t)bz * pstride;
    const int tid = threadIdx.x, lane = tid & 63, wave = tid >> 6;
    const int wm = wave >> 1, wn = wave & 1, quad = lane >> 4, l16 = lane & 15;
    const bool addb = (bz == 0);
    #pragma unroll
    for (int mt = 0; mt < 4; ++mt)
        #pragma unroll
        for (int nt = 0; nt < 4; ++nt) {
            size_t col = bN + wn * 64 + nt * 16 + l16;
            float bcol = addb ? bias[col] : 0.f;
            #pragma unroll
            for (int r = 0; r < 4; ++r) {
                size_t row = bM + wm * 64 + mt * 16 + quad * 4 + r;
                P[row * ldc + col] = acc[mt][nt][r] + bcol;
            }
        }
}

// ---------------------------------------------------------------------------
// Flash attention: one block = one (b,h) x 64 q-rows (QBLK=64, 16 rows/wave).
// 256 thr (4 waves). Round-5 lesson: at QBLK=128 the per-wave accumulator
// state (Sacc 64 + Oacc 32 f32 in the unified acc file, on top of ~116 arch
// VGPRs) totaled ~212 regs -> 2 waves/SIMD -> only 2 of 3 LDS-feasible
// blocks resident (17% occupancy, latency-bound with nothing saturated).
// QBLK=64 halves Sacc/Oacc/aq (total ~145 regs) and Ps (LDS 43008B):
// 3 blocks/CU both by LDS and VGPR. Softmax shfl work per chip UNCHANGED
// (half per wave x 2x waves). K/V re-reads double but are L2/L3-resident.
// __launch_bounds__(256,3): 3-wave target (<=170 total) now exceeds the
// live set, so no spill (round-1's spill came from forcing ~212 into 170).
// All tiles XOR-swizzled at 16B-slot granularity (slot ^= row&7).
// P round-trips LDS in two 64-key halves (wave-private rows, no barrier).
// Softmax in exp2 domain with additive bf16 mask bias folded via fma.
// ---------------------------------------------------------------------------
__global__ __launch_bounds__(256, 3) void flash_attn(
    const u16* __restrict__ qkv, const u16* __restrict__ vt,
    const int* __restrict__ mask, u16* __restrict__ attout)
{
    __shared__ u16 Ks[128 * 64];    // [key][d]   128B rows, swizzled   16KB
    __shared__ u16 Vs[64 * 128];    // [d][key]   256B rows, swizzled   16KB
    __shared__ u16 Ps[64 * 64];     // [q][key-half] 128B rows, swizzled 8KB
    __shared__ u16 Msb[1024];       // additive bias bf16: masked -> -1e9, else 0

    const int bh = blockIdx.y;
    const int b = bh / 12, h = bh % 12;
    const int q0 = blockIdx.x * 64;
    const int tid = threadIdx.x, lane = tid & 63, wave = tid >> 6;
    const int quad = lane >> 4, l16 = lane & 15;
    const int sw = l16 & 7;         // read-side swizzle key (row&7 == l16&7)

    for (int i = tid; i < 1024; i += 256)
        Msb[i] = (mask[b * 1024 + i] != 0) ? f2b(-1e9f) : (u16)0;

    bf16x8 aq[2];
    #pragma unroll
    for (int s = 0; s < 2; ++s)
        aq[s] = *(const bf16x8*)(qkv + (size_t)(b * 1024 + q0 + wave * 16 + l16) * 2304
                                  + h * 192 + s * 32 + quad * 8);

    const float SC2 = 0.18033688011112042f;   // 0.125 * log2(e): softmax in exp2 domain

    float mi[4], li[4];
    f32x4 Oacc[4] = {};
    #pragma unroll
    for (int r = 0; r < 4; ++r) { mi[r] = -3e38f; li[r] = 0.f; }

    for (int kt = 0; kt < 8; ++kt) {
        u32x4 kreg[4], vreg[4];
        #pragma unroll
        for (int i = 0; i < 4; ++i) {
            int id = i * 256 + tid, row = id >> 3, ch = id & 7;
            kreg[i] = *(const u32x4*)(qkv + (size_t)(b * 1024 + kt * 128 + row) * 2304 + h * 192 + 64 + ch * 8);
        }
        #pragma unroll
        for (int i = 0; i < 4; ++i) {
            int id = i * 256 + tid, row = id >> 4, ch = id & 15;
            vreg[i] = *(const u32x4*)(vt + (size_t)bh * 65536 + (size_t)row * 1024 + kt * 128 + ch * 8);
        }
        __syncthreads();
        #pragma unroll
        for (int i = 0; i < 4; ++i) {
            int id = i * 256 + tid, row = id >> 3, ch = id & 7;
            *(u32x4*)(Ks + row * 64 + ((ch ^ (row & 7)) * 8)) = kreg[i];
        }
        #pragma unroll
        for (int i = 0; i < 4; ++i) {
            int id = i * 256 + tid, row = id >> 4, ch = id & 15;
            *(u32x4*)(Vs + row * 128 + ((ch ^ (row & 7)) * 8)) = vreg[i];
        }
        __syncthreads();

        f32x4 Sacc[8] = {};
        #pragma unroll
        for (int s = 0; s < 2; ++s) {
            bf16x8 kf[8];
            #pragma unroll
            for (int nt = 0; nt < 8; ++nt)
                kf[nt] = *(const bf16x8*)(Ks + (nt * 16 + l16) * 64 + (((s * 4 + quad) ^ sw) * 8));
            #pragma unroll
            for (int nt = 0; nt < 8; ++nt)
                Sacc[nt] = __builtin_amdgcn_mfma_f32_16x16x32_bf16(aq[s], kf[nt], Sacc[nt], 0, 0, 0);
        }

        // scale (exp2 domain) + additive mask bias in one fma per element
        float bias[8];
        #pragma unroll
        for (int nt = 0; nt < 8; ++nt) bias[nt] = b2f(Msb[kt * 128 + nt * 16 + l16]);
        #pragma unroll
        for (int nt = 0; nt < 8; ++nt)
            #pragma unroll
            for (int r = 0; r < 4; ++r)
                Sacc[nt][r] = fmaf(Sacc[nt][r], SC2, bias[nt]);

        float al[4];
        #pragma unroll
        for (int r = 0; r < 4; ++r) {
            float rm = fmaxf(
                fmaxf(fmaxf(Sacc[0][r], Sacc[1][r]), fmaxf(Sacc[2][r], Sacc[3][r])),
                fmaxf(fmaxf(Sacc[4][r], Sacc[5][r]), fmaxf(Sacc[6][r], Sacc[7][r])));
            #pragma unroll
            for (int o = 8; o; o >>= 1) rm = fmaxf(rm, __shfl_xor(rm, o));
            float mn = fmaxf(mi[r], rm);
            al[r] = fexp2(mi[r] - mn);
            mi[r] = mn;
            float rs = 0.f;
            #pragma unroll
            for (int nt = 0; nt < 8; ++nt) {
                float pv = fexp2(Sacc[nt][r] - mn);
                rs += pv;
                Sacc[nt][r] = pv;
            }
            #pragma unroll
            for (int o = 8; o; o >>= 1) rs += __shfl_xor(rs, o);
            li[r] = li[r] * al[r] + rs;
        }
        #pragma unroll
        for (int ntv = 0; ntv < 4; ++ntv)
            #pragma unroll
            for (int r = 0; r < 4; ++r) Oacc[ntv][r] *= al[r];

        // P -> LDS -> PV in two 64-key halves (wave-private rows; DS in-order
        // per wave + compiler aliasing keeps write-after-read correct)
        #pragma unroll
        for (int hf = 0; hf < 2; ++hf) {
            const int rowb = wave * 16 + quad * 4;
            #pragma unroll
            for (int n4 = 0; n4 < 4; ++n4) {
                const int slot = n4 * 2 + (l16 >> 3);
                #pragma unroll
                for (int r = 0; r < 4; ++r) {
                    const int row = rowb + r;
                    Ps[row * 64 + ((slot ^ (row & 7)) * 8) + sw] = f2b(Sacc[hf * 4 + n4][r]);
                }
            }
            #pragma unroll
            for (int s2h = 0; s2h < 2; ++s2h) {
                const int s2 = hf * 2 + s2h;
                bf16x8 vf[4];
                #pragma unroll
                for (int ntv = 0; ntv < 4; ++ntv)
                    vf[ntv] = *(const bf16x8*)(Vs + (ntv * 16 + l16) * 128 + (((s2 * 4 + quad) ^ sw) * 8));
                bf16x8 pf = *(const bf16x8*)(Ps + (wave * 16 + l16) * 64 + (((s2h * 4 + quad) ^ sw) * 8));
                #pragma unroll
                for (int ntv = 0; ntv < 4; ++ntv)
                    Oacc[ntv] = __builtin_amdgcn_mfma_f32_16x16x32_bf16(pf, vf[ntv], Oacc[ntv], 0, 0, 0);
            }
        }
    }

    #pragma unroll
    for (int r = 0; r < 4; ++r) {
        float inv = 1.0f / li[r];
        int s = q0 + wave * 16 + quad * 4 + r;
        #pragma unroll
        for (int ntv = 0; ntv < 4; ++ntv)
            attout[((size_t)(b * 1024 + s)) * 768 + h * 64 + ntv * 16 + l16] = f2b(Oacc[ntv][r] * inv);
    }
}

// x[b,s,:] = (token_emb[id] + pos_emb[s]) * sqrt(768)  (dual dtype)
__global__ __launch_bounds__(256) void embed_kernel(
    const int* __restrict__ ids, const void* __restrict__ tok,
    const void* __restrict__ pos, float* __restrict__ x, const int* __restrict__ flag)
{
    const int e  = blockIdx.x * 256 + threadIdx.x;
    const int bs = e / 192;
    const int d  = (e - bs * 192) * 4;
    const int s  = bs & 1023;
    const int id = ids[bs];
    float t[4], p4[4];
    if (flag[0]) {
        const u16* tb = (const u16*)tok + (size_t)id * 768 + d;
        const u16* pb = (const u16*)pos + (size_t)s  * 768 + d;
        #pragma unroll
        for (int j = 0; j < 4; ++j) { t[j] = b2f(tb[j]); p4[j] = b2f(pb[j]); }
    } else {
        const float* tb = (const float*)tok + (size_t)id * 768 + d;
        const float* pb = (const float*)pos + (size_t)s  * 768 + d;
        #pragma unroll
        for (int j = 0; j < 4; ++j) { t[j] = tb[j]; p4[j] = pb[j]; }
    }
    float* xo = x + (size_t)bs * 768 + d;
    #pragma unroll
    for (int j = 0; j < 4; ++j) xo[j] = (t[j] + p4[j]) * 27.7128129211020f;
}

// LayerNorm with optional split-K partial fold: if part != nullptr,
// x[row] += part0[row] + part1[row] (written back: x is the residual),
// then LN(x[row]) -> out. part1 = part + 6291456 elements.
__global__ __launch_bounds__(256) void layernorm_kernel(
    float* __restrict__ x, const float* __restrict__ part,
    const float* __restrict__ sc, const float* __restrict__ bi,
    u16* __restrict__ out)
{
    __shared__ float red[4];
    const size_t row = blockIdx.x;
    float* xr = x + row * 768;
    const int tid = threadIdx.x;
    float v0 = xr[tid], v1 = xr[tid + 256], v2 = xr[tid + 512];
    if (part) {
        const float* p0 = part + row * 768;
        const float* p1 = p0 + 6291456;
        v0 += p0[tid]       + p1[tid];
        v1 += p0[tid + 256] + p1[tid + 256];
        v2 += p0[tid + 512] + p1[tid + 512];
        xr[tid] = v0; xr[tid + 256] = v1; xr[tid + 512] = v2;
    }
    float s = blockReduceSum(v0 + v1 + v2, red, tid);
    float mean = s * (1.0f / 768.0f);
    float d0 = v0 - mean, d1 = v1 - mean, d2 = v2 - mean;
    float q = blockReduceSum(d0 * d0 + d1 * d1 + d2 * d2, red, tid);
    float rstd = rsqrtf(q * (1.0f / 768.0f) + 1e-5f);
    u16* orow = out + row * 768;
    orow[tid]       = f2b(d0 * rstd * sc[tid]       + bi[tid]);
    orow[tid + 256] = f2b(d1 * rstd * sc[tid + 256] + bi[tid + 256]);
    orow[tid + 512] = f2b(d2 * rstd * sc[tid + 512] + bi[tid + 512]);
}

// W (Kd,Nd) [fp32 or bf16 per flag] -> Wt (Nd,Kd) bf16; one layer per launch
__global__ __launch_bounds__(256) void transpose_w_kernel(
    const void* __restrict__ W, size_t off, u16* __restrict__ Wt,
    int Kd, int Nd, const int* __restrict__ flag)
{
    __shared__ u16 tile[32][34];
    const int n0 = blockIdx.x * 32, k0 = blockIdx.y * 32;
    const int tx = threadIdx.x & 31, ty = threadIdx.x >> 5;
    const int fl = flag[0];
    #pragma unroll
    for (int i = 0; i < 4; ++i) {
        size_t idx = off + (size_t)(k0 + ty + i * 8) * Nd + n0 + tx;
        u16 val = fl ? ((const u16*)W)[idx] : f2b(((const float*)W)[idx]);
        tile[ty + i * 8][tx] = val;
    }
    __syncthreads();
    #pragma unroll
    for (int i = 0; i < 4; ++i)
        Wt[(size_t)(n0 + ty + i * 8) * Kd + k0 + tx] = tile[tx][ty + i * 8];
}

// vt[bh, d, t] = qkv[b, t, h*192+128+d]
__global__ __launch_bounds__(256) void build_vt_kernel(
    const u16* __restrict__ qkv, u16* __restrict__ vt)
{
    __shared__ u16 tile[64][72];
    const int bh = blockIdx.y;
    const int b = bh / 12, h = bh % 12;
    const int t0 = blockIdx.x * 64;
    const int tid = threadIdx.x;
    const int tl = tid >> 2;
    const int d4 = (tid & 3) * 16;
    const u16* src = qkv + (size_t)(b * 1024 + t0 + tl) * 2304 + h * 192 + 128 + d4;
    *(u32x4*)(&tile[tl][d4])     = *(const u32x4*)(src);
    *(u32x4*)(&tile[tl][d4 + 8]) = *(const u32x4*)(src + 8);
    __syncthreads();
    const int dd = tid >> 2;
    const int tstart = (tid & 3) * 16;
    union { u16 us[16]; u32x4 v[2]; } pk;
    #pragma unroll
    for (int j = 0; j < 16; ++j) pk.us[j] = tile[tstart + j][dd];
    u16* dst = vt + ((size_t)bh * 64 + dd) * 1024 + t0 + tstart;
    *(u32x4*)(dst)     = pk.v[0];
    *(u32x4*)(dst + 8) = pk.v[1];
}

// pooled = LN(x[:,0,:] + F0 + F1); out = pooled @ cls_w + cls_b
// (folds the final ff2 partials at row (b,0) only — rest of x is dead)
__global__ __launch_bounds__(256) void pooled_cls_kernel(
    const float* __restrict__ x, const float* __restrict__ part,
    const float* __restrict__ hs, const float* __restrict__ hb,
    const float* __restrict__ cw, const float* __restrict__ cb, void* __restrict__ dout,
    const int* __restrict__ flag)
{
    __shared__ float red[4];
    __shared__ float pooled[768];
    const int b = blockIdx.x;
    const float* xr = x + (size_t)b * 1024 * 768;
    const float* p0 = part + (size_t)b * 1024 * 768;
    const float* p1 = p0 + 6291456;
    const int tid = threadIdx.x;
    float v0 = xr[tid]       + p0[tid]       + p1[tid];
    float v1 = xr[tid + 256] + p0[tid + 256] + p1[tid + 256];
    float v2 = xr[tid + 512] + p0[tid + 512] + p1[tid + 512];
    float s = blockReduceSum(v0 + v1 + v2, red, tid);
    float mean = s * (1.0f / 768.0f);
    float d0 = v0 - mean, d1 = v1 - mean, d2 = v2 - mean;
    float q = blockReduceSum(d0 * d0 + d1 * d1 + d2 * d2, red, tid);
    float rstd = rsqrtf(q * (1.0f / 768.0f) + 1e-5f);
    pooled[tid]       = d0 * rstd * hs[tid]       + hb[tid];
    pooled[tid + 256] = d1 * rstd * hs[tid + 256] + hb[tid + 256];
    pooled[tid + 512] = d2 * rstd * hs[tid + 512] + hb[tid + 512];
    __syncthreads();
    float q0 = 0.f, q1 = 0.f;
    for (int c = tid; c < 768; c += 256) {
        float pv = pooled[c];
        q0 += pv * cw[2 * c];
        q1 += pv * cw[2 * c + 1];
    }
    q0 = blockReduceSum(q0, red, tid);
    q1 = blockReduceSum(q1, red, tid);
    if (tid == 0) {
        float o0 = q0 + cb[0], o1 = q1 + cb[1];
        if (flag[0]) {
            ((u16*)dout)[b * 2 + 0] = f2b(o0);
            ((u16*)dout)[b * 2 + 1] = f2b(o1);
        } else {
            ((float*)dout)[b * 2 + 0] = o0;
            ((float*)dout)[b * 2 + 1] = o1;
        }
    }
}

extern "C" void kernel_launch(void* const* d_in, const int* in_sizes, int n_in,
                              void* d_out, int out_size, void* d_ws, size_t ws_size,
                              hipStream_t stream)
{
    const int* ids  = (const int*)d_in[0];
    const int* mask = (const int*)d_in[1];
    const void* tok   = d_in[2];
    const void* pos   = d_in[3];
    const void* qkv_w = d_in[4];
    const void* qkv_b = d_in[5];
    const void* out_w = d_in[6];
    const void* out_b = d_in[7];
    const void* n1_s  = d_in[8];
    const void* n1_b  = d_in[9];
    const void* ff1_w = d_in[10];
    const void* ff1_b = d_in[11];
    const void* ff2_w = d_in[12];
    const void* ff2_b = d_in[13];
    const void* n2_s  = d_in[14];
    const void* n2_b  = d_in[15];
    const void* hln_s = d_in[16];
    const void* hln_b = d_in[17];
    const void* cls_w = d_in[18];
    const void* cls_b = d_in[19];

    char* p = (char*)d_ws;
    auto alloc = [&](size_t bytes) -> char* {
        char* r = p; p += (bytes + 255) & ~(size_t)255; return r;
    };
    float* x      = (float*)alloc(6291456ull * 4);    // residual (B*S*D) fp32       25.2MB
    u16*   h      = (u16*)  alloc(6291456ull * 2);    // LN out / attout (shared)    12.6MB
    u16*   qkvB   = (u16*)  alloc(18874368ull * 2);   // qkv bf16 (B*S*2304)         37.7MB
    u16*   vt     = (u16*)  alloc(6291456ull * 2);    // V^T (96,64,1024)            12.6MB
    u16*   ffmid  = (u16*)  alloc(25165824ull * 2);   // (8192,3072) bf16            50.3MB
    u16*   wqkvT  = (u16*)  alloc(1769472ull * 2);    // (2304,768) one layer
    u16*   woutT  = (u16*)  alloc(589824ull * 2);     // (768,768)
    u16*   wff1T  = (u16*)  alloc(2359296ull * 2);    // (3072,768)
    u16*   wff2T  = (u16*)  alloc(2359296ull * 2);    // (768,3072)
    float* params = (float*)alloc(62978ull * 4);      // converted fp32 param vectors
    int*   flag   = (int*)  alloc(256);
    u16*   attout = h;                                 // aliases h (disjoint lifetime)

    // Split-K partial buffers (each 2 x 6291456 fp32 = 50.33MB), recycled
    // from dead regions (no new workspace):
    //  - attn-out partials -> ffmid region (dead between attn-out and ff1)
    //  - ff2 partials      -> qkvB+vt region (dead after flash_attn; sizes
    //    37748736+12582912 = 50331648B, contiguous by alloc order)
    float* Apart = (float*)ffmid;
    float* Fpart = (float*)qkvB;

    float* P_qkv_b = params + 0;
    float* P_out_b = params + 13824;
    float* P_n1_s  = params + 18432;
    float* P_n1_b  = params + 23040;
    float* P_ff1_b = params + 27648;
    float* P_ff2_b = params + 46080;
    float* P_n2_s  = params + 50688;
    float* P_n2_b  = params + 55296;
    float* P_hln_s = params + 59904;
    float* P_hln_b = params + 60672;
    float* P_cls_w = params + 61440;
    float* P_cls_b = params + 62976;

    detect_kernel<<<1, 256, 0, stream>>>(tok, flag);

    auto cvt = [&](const void* src, float* dst, int n) {
        to_f32_kernel<<<(n + 255) / 256, 256, 0, stream>>>(src, dst, n, flag);
    };
    cvt(qkv_b, P_qkv_b, 13824);  cvt(out_b, P_out_b, 4608);
    cvt(n1_s,  P_n1_s,  4608);   cvt(n1_b,  P_n1_b,  4608);
    cvt(ff1_b, P_ff1_b, 18432);  cvt(ff2_b, P_ff2_b, 4608);
    cvt(n2_s,  P_n2_s,  4608);   cvt(n2_b,  P_n2_b,  4608);
    cvt(hln_s, P_hln_s, 768);    cvt(hln_b, P_hln_b, 768);
    cvt(cls_w, P_cls_w, 1536);   cvt(cls_b, P_cls_b, 2);

    embed_kernel<<<6144, 256, 0, stream>>>(ids, tok, pos, x, flag);

    for (int l = 0; l < 6; ++l) {
        transpose_w_kernel<<<dim3(72, 24), 256, 0, stream>>>(qkv_w, (size_t)l * 1769472, wqkvT, 768, 2304, flag);
        transpose_w_kernel<<<dim3(24, 24), 256, 0, stream>>>(out_w, (size_t)l * 589824,  woutT, 768, 768,  flag);
        transpose_w_kernel<<<dim3(96, 24), 256, 0, stream>>>(ff1_w, (size_t)l * 2359296, wff1T, 768, 3072, flag);
        transpose_w_kernel<<<dim3(24, 96), 256, 0, stream>>>(ff2_w, (size_t)l * 2359296, wff2T, 3072, 768, flag);

        // ln1: fold previous layer's ff2 partials (l>0); writes x + h
        layernorm_kernel<<<8192, 256, 0, stream>>>(x, (l == 0) ? nullptr : Fpart,
                                                   P_n1_s + l * 768, P_n1_b + l * 768, h);
        gemm_std<0><<<dim3(18, 64), 256, 0, stream>>>(h, 768, wqkvT, 768,
                                                      P_qkv_b + l * 2304, qkvB, 2304, 768);
        build_vt_kernel<<<dim3(16, 96), 256, 0, stream>>>(qkvB, vt);
        flash_attn<<<dim3(16, 96), 256, 0, stream>>>(qkvB, vt, mask, attout);
        // attn-out: partials into ffmid region (plain stores, no atomics)
        gemm_partial<<<dim3(6, 64, 2), 256, 0, stream>>>(attout, 768, woutT, 768,
                                                         P_out_b + l * 768, Apart, 6291456, 768, 384);
        // ln2: fold attn-out partials; writes x + h
        layernorm_kernel<<<8192, 256, 0, stream>>>(x, Apart,
                                                   P_n2_s + l * 768, P_n2_b + l * 768, h);
        gemm_std<1><<<dim3(24, 64), 256, 0, stream>>>(h, 768, wff1T, 768,
                                                      P_ff1_b + l * 3072, ffmid, 3072, 768);
        // ff2: partials into qkvB+vt region (folded by next ln1 / pooled)
        gemm_partial<<<dim3(6, 64, 2), 256, 0, stream>>>(ffmid, 3072, wff2T, 3072,
                                                         P_ff2_b + l * 768, Fpart, 6291456, 768, 1536);
    }
    pooled_cls_kernel<<<8, 256, 0, stream>>>(x, Fpart, P_hln_s, P_hln_b, P_cls_w, P_cls_b, d_out, flag);
}